// Round 1
// baseline (1941.064 us; speedup 1.0000x reference)
//
#include <hip/hip_runtime.h>
#include <math.h>

#define N_TOK 131072
#define HD    256
#define DS    32
#define DG    32
#define FM    64
#define NE    4
#define FF    512
#define TT    16   // tokens per expert block

__device__ __forceinline__ float gelu_f(float x) {
    // exact erf GELU (reference uses approximate=False)
    return 0.5f * x * (1.0f + erff(x * 0.70710678118654752f));
}

// ---------------------------------------------------------------------------
// Kernel 1: router. 256 threads = 4 waves, one token per wave.
// LN(h) -> gelu(geom) -> gelu(fuse(concat)) -> logits -> softmax -> top1.
// ---------------------------------------------------------------------------
__global__ __launch_bounds__(256) void router_kernel(
    const float* __restrict__ h, const float* __restrict__ tok_emb,
    const float* __restrict__ ln_g, const float* __restrict__ ln_b,
    const float* __restrict__ geom_w, const float* __restrict__ geom_b,
    const float* __restrict__ fuse_w, const float* __restrict__ fuse_b,
    const float* __restrict__ router_w, const float* __restrict__ router_b,
    int* __restrict__ top_idx, float* __restrict__ top_prob,
    int* __restrict__ counts, float* __restrict__ importance)
{
    __shared__ float sh_ln[4][HD];
    __shared__ float sh_c[4][DS + DG];
    __shared__ float sh_u[4][FM];
    __shared__ float s_imp[NE];
    __shared__ int   s_cnt[NE];

    const int tid  = threadIdx.x;
    const int wv   = tid >> 6;
    const int lane = tid & 63;
    const int tok  = blockIdx.x * 4 + wv;

    if (tid < NE) { s_imp[tid] = 0.f; s_cnt[tid] = 0; }

    // ---- LayerNorm over 256 elems (4 per lane) ----
    float4 hv = *reinterpret_cast<const float4*>(&h[(size_t)tok * HD + lane * 4]);
    float s = hv.x + hv.y + hv.z + hv.w;
    #pragma unroll
    for (int off = 32; off; off >>= 1) s += __shfl_xor(s, off);
    float mu = s * (1.0f / HD);
    float d0 = hv.x - mu, d1 = hv.y - mu, d2 = hv.z - mu, d3 = hv.w - mu;
    float v = d0*d0 + d1*d1 + d2*d2 + d3*d3;
    #pragma unroll
    for (int off = 32; off; off >>= 1) v += __shfl_xor(v, off);
    float rstd = rsqrtf(v * (1.0f / HD) + 1e-5f);

    float4 g4 = *reinterpret_cast<const float4*>(&ln_g[lane * 4]);
    float4 b4 = *reinterpret_cast<const float4*>(&ln_b[lane * 4]);
    float4 ln;
    ln.x = d0 * rstd * g4.x + b4.x;
    ln.y = d1 * rstd * g4.y + b4.y;
    ln.z = d2 * rstd * g4.z + b4.z;
    ln.w = d3 * rstd * g4.w + b4.w;
    *reinterpret_cast<float4*>(&sh_ln[wv][lane * 4]) = ln;

    if (lane < DS) sh_c[wv][lane] = tok_emb[(size_t)tok * DS + lane];
    __syncthreads();

    // ---- geom: [256] @ [256,32], split K in half across lane pairs ----
    {
        const int j = lane & 31, half = lane >> 5;
        const float* hl = sh_ln[wv];
        float acc = 0.f;
        const int k0 = half * 128;
        for (int k = k0; k < k0 + 128; ++k)
            acc = fmaf(hl[k], geom_w[k * DG + j], acc);
        acc += __shfl_xor(acc, 32);
        if (half == 0) sh_c[wv][DS + j] = gelu_f(acc + geom_b[j]);
    }
    __syncthreads();

    // ---- fuse: [64] @ [64,64] ----
    {
        const float* c = sh_c[wv];
        float a = fuse_b[lane];
        #pragma unroll 8
        for (int k = 0; k < DS + DG; ++k)
            a = fmaf(c[k], fuse_w[k * FM + lane], a);
        sh_u[wv][lane] = gelu_f(a);
    }
    __syncthreads();

    // ---- logits: [64] @ [64,4] (lanes 0..3) ----
    float lg = 0.f;
    if (lane < NE) {
        const float* u = sh_u[wv];
        lg = router_b[lane];
        #pragma unroll 8
        for (int k = 0; k < FM; ++k)
            lg = fmaf(u[k], router_w[k * NE + lane], lg);
    }
    float l0 = __shfl(lg, 0), l1 = __shfl(lg, 1),
          l2 = __shfl(lg, 2), l3 = __shfl(lg, 3);
    float m  = fmaxf(fmaxf(l0, l1), fmaxf(l2, l3));
    float e0 = expf(l0 - m), e1 = expf(l1 - m), e2 = expf(l2 - m), e3 = expf(l3 - m);
    float inv = 1.0f / (e0 + e1 + e2 + e3);
    float p0 = e0 * inv, p1 = e1 * inv, p2 = e2 * inv, p3 = e3 * inv;
    int bi = 0; float bp = p0;
    if (p1 > bp) { bp = p1; bi = 1; }
    if (p2 > bp) { bp = p2; bi = 2; }
    if (p3 > bp) { bp = p3; bi = 3; }

    if (lane == 0) {
        top_idx[tok]  = bi;
        top_prob[tok] = bp;
        atomicAdd(&s_imp[0], p0); atomicAdd(&s_imp[1], p1);
        atomicAdd(&s_imp[2], p2); atomicAdd(&s_imp[3], p3);
        atomicAdd(&s_cnt[bi], 1);
    }
    __syncthreads();
    if (tid < NE) {
        atomicAdd(&importance[tid], s_imp[tid]);
        atomicAdd(&counts[tid], s_cnt[tid]);
    }
}

// ---------------------------------------------------------------------------
// Kernel 2: exclusive scan of the 4 counts + load-balance loss.
// ---------------------------------------------------------------------------
__global__ void scan_lb_kernel(const int* __restrict__ counts,
                               const float* __restrict__ importance,
                               int* __restrict__ offsets,
                               float* __restrict__ d_out_lb)
{
    int c0 = counts[0], c1 = counts[1], c2 = counts[2], c3 = counts[3];
    offsets[0] = 0;
    offsets[1] = c0;
    offsets[2] = c0 + c1;
    offsets[3] = c0 + c1 + c2;
    double num = (double)importance[0] * c0 + (double)importance[1] * c1 +
                 (double)importance[2] * c2 + (double)importance[3] * c3;
    double lb = (double)NE * num / ((double)N_TOK * (double)N_TOK + 1e-8);
    *d_out_lb = (float)lb;
}

// ---------------------------------------------------------------------------
// Kernel 3: bucket tokens by expert (order stable-enough; order irrelevant).
// ---------------------------------------------------------------------------
__global__ __launch_bounds__(256) void place_kernel(
    const int* __restrict__ top_idx, const int* __restrict__ offsets,
    int* __restrict__ cursors, int* __restrict__ order)
{
    __shared__ int lcnt[NE];
    __shared__ int lbase[NE];
    const int tid = threadIdx.x;
    const int i   = blockIdx.x * 256 + tid;
    if (tid < NE) lcnt[tid] = 0;
    __syncthreads();
    const int e = top_idx[i];
    const int r = atomicAdd(&lcnt[e], 1);
    __syncthreads();
    if (tid < NE) lbase[tid] = (lcnt[tid] > 0) ? atomicAdd(&cursors[tid], lcnt[tid]) : 0;
    __syncthreads();
    order[offsets[e] + lbase[e] + r] = i;
}

// ---------------------------------------------------------------------------
// Kernel 4: grouped expert FFN. One block = 16 tokens of ONE expert.
// Layer1: [16,256]@[256,512]+b -> gelu -> LDS. Layer2: [16,512]@[512,256]+b.
// Per-thread register tile: 4 tokens x 8 cols (L1) / 4 tokens x 4 cols (L2).
// ---------------------------------------------------------------------------
__global__ __launch_bounds__(256) void expert_kernel(
    const float* __restrict__ h,
    const float* __restrict__ w1, const float* __restrict__ b1,
    const float* __restrict__ w2, const float* __restrict__ b2,
    const float* __restrict__ top_prob,
    const int* __restrict__ order, const int* __restrict__ counts,
    const int* __restrict__ offsets, float* __restrict__ out)
{
    __shared__ float sh_h[TT][HD];   // 16 KB (original h, also residual source)
    __shared__ float sh_a[TT][FF];   // 32 KB (gelu(layer1))
    __shared__ int   s_tok[TT];

    const int tid = threadIdx.x;

    // map blockIdx -> (expert e, chunk c)
    int c = blockIdx.x, e;
    for (e = 0; e < NE; ++e) {
        int nch = (counts[e] + TT - 1) / TT;
        if (c < nch) break;
        c -= nch;
    }
    if (e >= NE) return;
    const int cnt  = counts[e];
    const int base = offsets[e] + c * TT;
    const int nt   = min(TT, cnt - c * TT);

    if (tid < TT) s_tok[tid] = (tid < nt) ? order[base + tid] : -1;
    __syncthreads();

    // gather h rows -> LDS (zeros for inactive slots)
    #pragma unroll
    for (int it = 0; it < 4; ++it) {
        int idx = tid + it * 256;          // 0..1023 float4 slots
        int r = idx >> 6, q = idx & 63;
        int t = s_tok[r];
        float4 val = make_float4(0.f, 0.f, 0.f, 0.f);
        if (t >= 0) val = *reinterpret_cast<const float4*>(&h[(size_t)t * HD + q * 4]);
        *reinterpret_cast<float4*>(&sh_h[r][q * 4]) = val;
    }
    __syncthreads();

    const int tx = tid & 63;   // column group
    const int ty = tid >> 6;   // token group (== wave id)
    const float* W1 = w1 + (size_t)e * HD * FF;
    const float* W2 = w2 + (size_t)e * FF * HD;

    // ---------------- layer 1 ----------------
    float acc[4][8];
    {
        float4 bb0 = *reinterpret_cast<const float4*>(&b1[e * FF + tx * 8]);
        float4 bb1 = *reinterpret_cast<const float4*>(&b1[e * FF + tx * 8 + 4]);
        #pragma unroll
        for (int t = 0; t < 4; ++t) {
            acc[t][0] = bb0.x; acc[t][1] = bb0.y; acc[t][2] = bb0.z; acc[t][3] = bb0.w;
            acc[t][4] = bb1.x; acc[t][5] = bb1.y; acc[t][6] = bb1.z; acc[t][7] = bb1.w;
        }
    }
    for (int k4 = 0; k4 < HD / 4; ++k4) {
        float hbuf[4][4];
        #pragma unroll
        for (int t = 0; t < 4; ++t)
            *reinterpret_cast<float4*>(hbuf[t]) =
                *reinterpret_cast<const float4*>(&sh_h[ty * 4 + t][k4 * 4]);
        #pragma unroll
        for (int kk = 0; kk < 4; ++kk) {
            const float* wrow = &W1[(size_t)(k4 * 4 + kk) * FF + tx * 8];
            float4 wA = *reinterpret_cast<const float4*>(wrow);
            float4 wB = *reinterpret_cast<const float4*>(wrow + 4);
            #pragma unroll
            for (int t = 0; t < 4; ++t) {
                float hs = hbuf[t][kk];
                acc[t][0] = fmaf(hs, wA.x, acc[t][0]);
                acc[t][1] = fmaf(hs, wA.y, acc[t][1]);
                acc[t][2] = fmaf(hs, wA.z, acc[t][2]);
                acc[t][3] = fmaf(hs, wA.w, acc[t][3]);
                acc[t][4] = fmaf(hs, wB.x, acc[t][4]);
                acc[t][5] = fmaf(hs, wB.y, acc[t][5]);
                acc[t][6] = fmaf(hs, wB.z, acc[t][6]);
                acc[t][7] = fmaf(hs, wB.w, acc[t][7]);
            }
        }
    }
    #pragma unroll
    for (int t = 0; t < 4; ++t) {
        float4 o0, o1;
        o0.x = gelu_f(acc[t][0]); o0.y = gelu_f(acc[t][1]);
        o0.z = gelu_f(acc[t][2]); o0.w = gelu_f(acc[t][3]);
        o1.x = gelu_f(acc[t][4]); o1.y = gelu_f(acc[t][5]);
        o1.z = gelu_f(acc[t][6]); o1.w = gelu_f(acc[t][7]);
        *reinterpret_cast<float4*>(&sh_a[ty * 4 + t][tx * 8])     = o0;
        *reinterpret_cast<float4*>(&sh_a[ty * 4 + t][tx * 8 + 4]) = o1;
    }
    __syncthreads();

    // ---------------- layer 2 ----------------
    float acc2[4][4];
    {
        float4 bb = *reinterpret_cast<const float4*>(&b2[e * HD + tx * 4]);
        #pragma unroll
        for (int t = 0; t < 4; ++t) {
            acc2[t][0] = bb.x; acc2[t][1] = bb.y; acc2[t][2] = bb.z; acc2[t][3] = bb.w;
        }
    }
    for (int k4 = 0; k4 < FF / 4; ++k4) {
        float abuf[4][4];
        #pragma unroll
        for (int t = 0; t < 4; ++t)
            *reinterpret_cast<float4*>(abuf[t]) =
                *reinterpret_cast<const float4*>(&sh_a[ty * 4 + t][k4 * 4]);
        #pragma unroll
        for (int kk = 0; kk < 4; ++kk) {
            float4 w = *reinterpret_cast<const float4*>(&W2[(size_t)(k4 * 4 + kk) * HD + tx * 4]);
            #pragma unroll
            for (int t = 0; t < 4; ++t) {
                float av = abuf[t][kk];
                acc2[t][0] = fmaf(av, w.x, acc2[t][0]);
                acc2[t][1] = fmaf(av, w.y, acc2[t][1]);
                acc2[t][2] = fmaf(av, w.z, acc2[t][2]);
                acc2[t][3] = fmaf(av, w.w, acc2[t][3]);
            }
        }
    }

    // epilogue: h + 0.5 * top_prob * y  (scattered row stores, coalesced per row)
    #pragma unroll
    for (int t = 0; t < 4; ++t) {
        int tok = s_tok[ty * 4 + t];
        if (tok < 0) continue;
        float tp = 0.5f * top_prob[tok];
        float4 res = *reinterpret_cast<const float4*>(&sh_h[ty * 4 + t][tx * 4]);
        float4 o;
        o.x = res.x + tp * acc2[t][0];
        o.y = res.y + tp * acc2[t][1];
        o.z = res.z + tp * acc2[t][2];
        o.w = res.w + tp * acc2[t][3];
        *reinterpret_cast<float4*>(&out[(size_t)tok * HD + tx * 4]) = o;
    }
}

// ---------------------------------------------------------------------------
extern "C" void kernel_launch(void* const* d_in, const int* in_sizes, int n_in,
                              void* d_out, int out_size, void* d_ws, size_t ws_size,
                              hipStream_t stream)
{
    const float* h        = (const float*)d_in[0];
    const float* tok_emb  = (const float*)d_in[1];
    /* d_in[2] = is_mask: all zeros, unused by the reference math */
    const float* ln_g     = (const float*)d_in[3];
    const float* ln_b     = (const float*)d_in[4];
    const float* geom_w   = (const float*)d_in[5];
    const float* geom_b   = (const float*)d_in[6];
    const float* fuse_w   = (const float*)d_in[7];
    const float* fuse_b   = (const float*)d_in[8];
    const float* router_w = (const float*)d_in[9];
    const float* router_b = (const float*)d_in[10];
    const float* w1       = (const float*)d_in[11];
    const float* b1       = (const float*)d_in[12];
    const float* w2       = (const float*)d_in[13];
    const float* b2       = (const float*)d_in[14];
    float* out = (float*)d_out;

    // workspace layout (ints/floats, 4B units)
    int*   counts     = (int*)d_ws;                   // [4]
    float* importance = (float*)d_ws + 4;             // [4]
    int*   offsets    = (int*)d_ws + 8;               // [4]
    int*   cursors    = (int*)d_ws + 12;              // [4]
    int*   top_idx    = (int*)d_ws + 64;              // [N]
    float* top_prob   = (float*)d_ws + 64 + N_TOK;    // [N]
    int*   order      = (int*)d_ws + 64 + 2 * N_TOK;  // [N]

    hipMemsetAsync(d_ws, 0, 64 * sizeof(int), stream);

    router_kernel<<<N_TOK / 4, 256, 0, stream>>>(
        h, tok_emb, ln_g, ln_b, geom_w, geom_b, fuse_w, fuse_b,
        router_w, router_b, top_idx, top_prob, counts, importance);

    scan_lb_kernel<<<1, 1, 0, stream>>>(counts, importance, offsets,
                                        &out[(size_t)N_TOK * HD]);

    place_kernel<<<N_TOK / 256, 256, 0, stream>>>(top_idx, offsets, cursors, order);

    expert_kernel<<<N_TOK / TT + NE, 256, 0, stream>>>(
        h, w1, b1, w2, b2, top_prob, order, counts, offsets, out);
}

// Round 2
// 632.376 us; speedup vs baseline: 3.0695x; 3.0695x over previous
//
#include <hip/hip_runtime.h>
#include <hip/hip_bf16.h>
#include <math.h>

#define N_TOK 131072
#define HD    256
#define DS    32
#define DG    32
#define FM    64
#define NE    4
#define FF    512
#define MT    32   // tokens per expert block

typedef short  short8 __attribute__((ext_vector_type(8)));
typedef float  f32x4  __attribute__((ext_vector_type(4)));

__device__ __forceinline__ float gelu_f(float x) {
    return 0.5f * x * (1.0f + erff(x * 0.70710678118654752f));
}
__device__ __forceinline__ unsigned short f2bf(float x) {
    union { __hip_bfloat16 b; unsigned short u; } cv;
    cv.b = __float2bfloat16(x);
    return cv.u;
}

// ---------------------------------------------------------------------------
// Prep: transpose+convert w1 [E][K][N]->w1t [E][N][K] bf16, w2 likewise.
// ---------------------------------------------------------------------------
__global__ __launch_bounds__(256) void prep_weights_kernel(
    const float* __restrict__ w1, const float* __restrict__ w2,
    unsigned short* __restrict__ w1t, unsigned short* __restrict__ w2t)
{
    __shared__ float tile[32][33];
    int b = blockIdx.x;
    const float* src; unsigned short* dst; int K, Nn;
    if (b < 512) { int e = b >> 7; int t = b & 127;
        src = w1 + (size_t)e * HD * FF; dst = w1t + (size_t)e * HD * FF;
        K = HD; Nn = FF; b = t;
    } else { b -= 512; int e = b >> 7; int t = b & 127;
        src = w2 + (size_t)e * FF * HD; dst = w2t + (size_t)e * FF * HD;
        K = FF; Nn = HD; b = t;
    }
    int ntn = Nn / 32;
    int kt = b / ntn, nt = b % ntn;
    int r = threadIdx.x >> 3, c4 = threadIdx.x & 7;
    float4 v = *reinterpret_cast<const float4*>(&src[(size_t)(kt*32 + r) * Nn + nt*32 + c4*4]);
    tile[r][c4*4+0] = v.x; tile[r][c4*4+1] = v.y;
    tile[r][c4*4+2] = v.z; tile[r][c4*4+3] = v.w;
    __syncthreads();
    ushort4 o;
    o.x = f2bf(tile[c4*4+0][r]); o.y = f2bf(tile[c4*4+1][r]);
    o.z = f2bf(tile[c4*4+2][r]); o.w = f2bf(tile[c4*4+3][r]);
    *reinterpret_cast<ushort4*>(&dst[(size_t)(nt*32 + r) * K + kt*32 + c4*4]) = o;
}

// ---------------------------------------------------------------------------
// Router: 64 tokens/block, weights staged in LDS, fp32 throughout.
// ---------------------------------------------------------------------------
__global__ __launch_bounds__(256) void router_kernel(
    const float* __restrict__ h, const float* __restrict__ tok_emb,
    const float* __restrict__ ln_g, const float* __restrict__ ln_b,
    const float* __restrict__ geom_w, const float* __restrict__ geom_b,
    const float* __restrict__ fuse_w, const float* __restrict__ fuse_b,
    const float* __restrict__ router_w, const float* __restrict__ router_b,
    int* __restrict__ top_idx, float* __restrict__ top_prob,
    int* __restrict__ counts, float* __restrict__ importance)
{
    __shared__ float wg[HD * DG];       // 32 KB
    __shared__ float wf[(DS+DG) * FM];  // 16 KB
    __shared__ float wr[FM * NE];       // 1 KB
    __shared__ float sh_ln[4][HD];      // 4 KB
    __shared__ float sh_c[4][DS + DG];
    __shared__ float sh_u[4][FM];
    __shared__ float s_imp[NE];
    __shared__ int   s_cnt[NE];

    const int tid  = threadIdx.x;
    const int wv   = tid >> 6;
    const int lane = tid & 63;

    for (int i = tid; i < HD * DG;      i += 256) wg[i] = geom_w[i];
    for (int i = tid; i < (DS+DG) * FM; i += 256) wf[i] = fuse_w[i];
    if (tid < FM * NE) wr[tid] = router_w[tid];
    if (tid < NE) { s_imp[tid] = 0.f; s_cnt[tid] = 0; }

    const float4 rb = *reinterpret_cast<const float4*>(router_b);
    float4 g4 = *reinterpret_cast<const float4*>(&ln_g[lane * 4]);
    float4 b4 = *reinterpret_cast<const float4*>(&ln_b[lane * 4]);
    __syncthreads();

    const int base = blockIdx.x * 64 + wv * 16;
    for (int ti = 0; ti < 16; ++ti) {
        const int tok = base + ti;
        // ---- LayerNorm ----
        float4 hv = *reinterpret_cast<const float4*>(&h[(size_t)tok * HD + lane * 4]);
        float s = hv.x + hv.y + hv.z + hv.w;
        #pragma unroll
        for (int off = 32; off; off >>= 1) s += __shfl_xor(s, off);
        float mu = s * (1.0f / HD);
        float d0 = hv.x - mu, d1 = hv.y - mu, d2 = hv.z - mu, d3 = hv.w - mu;
        float v = d0*d0 + d1*d1 + d2*d2 + d3*d3;
        #pragma unroll
        for (int off = 32; off; off >>= 1) v += __shfl_xor(v, off);
        float rstd = rsqrtf(v * (1.0f / HD) + 1e-5f);
        float4 ln;
        ln.x = d0 * rstd * g4.x + b4.x;
        ln.y = d1 * rstd * g4.y + b4.y;
        ln.z = d2 * rstd * g4.z + b4.z;
        ln.w = d3 * rstd * g4.w + b4.w;
        *reinterpret_cast<float4*>(&sh_ln[wv][lane * 4]) = ln;
        if (lane < DS) sh_c[wv][lane] = tok_emb[(size_t)tok * DS + lane];
        __syncthreads();

        // ---- geom: lanes = 32 cols x 2 k-halves, 4 independent accs ----
        {
            const int j = lane & 31, half = lane >> 5;
            const float* hl = sh_ln[wv];
            float a0 = 0.f, a1 = 0.f, a2 = 0.f, a3 = 0.f;
            const int k0 = half * 128;
            #pragma unroll 8
            for (int k = k0; k < k0 + 128; k += 4) {
                a0 = fmaf(hl[k+0], wg[(k+0)*DG + j], a0);
                a1 = fmaf(hl[k+1], wg[(k+1)*DG + j], a1);
                a2 = fmaf(hl[k+2], wg[(k+2)*DG + j], a2);
                a3 = fmaf(hl[k+3], wg[(k+3)*DG + j], a3);
            }
            float acc = (a0 + a1) + (a2 + a3);
            acc += __shfl_xor(acc, 32);
            if (half == 0) sh_c[wv][DS + j] = gelu_f(acc + geom_b[j]);
        }
        __syncthreads();

        // ---- fuse: lane = col, 4 accs ----
        {
            const float* c = sh_c[wv];
            float a0 = 0.f, a1 = 0.f, a2 = 0.f, a3 = 0.f;
            #pragma unroll 4
            for (int k = 0; k < DS + DG; k += 4) {
                a0 = fmaf(c[k+0], wf[(k+0)*FM + lane], a0);
                a1 = fmaf(c[k+1], wf[(k+1)*FM + lane], a1);
                a2 = fmaf(c[k+2], wf[(k+2)*FM + lane], a2);
                a3 = fmaf(c[k+3], wf[(k+3)*FM + lane], a3);
            }
            sh_u[wv][lane] = gelu_f(((a0 + a1) + (a2 + a3)) + fuse_b[lane]);
        }
        __syncthreads();

        // ---- logits across all lanes: lane = (expert, k-chunk) ----
        const int ee = lane >> 4, kk = lane & 15;
        float pp = 0.f;
        #pragma unroll
        for (int i = 0; i < 4; ++i) {
            int k = kk * 4 + i;
            pp = fmaf(sh_u[wv][k], wr[k * NE + ee], pp);
        }
        pp += __shfl_xor(pp, 1);
        pp += __shfl_xor(pp, 2);
        pp += __shfl_xor(pp, 4);
        pp += __shfl_xor(pp, 8);
        float l0 = __shfl(pp, 0)  + rb.x;
        float l1 = __shfl(pp, 16) + rb.y;
        float l2 = __shfl(pp, 32) + rb.z;
        float l3 = __shfl(pp, 48) + rb.w;
        float m  = fmaxf(fmaxf(l0, l1), fmaxf(l2, l3));
        float e0 = expf(l0 - m), e1 = expf(l1 - m), e2 = expf(l2 - m), e3 = expf(l3 - m);
        float inv = 1.0f / (e0 + e1 + e2 + e3);
        float p0 = e0 * inv, p1 = e1 * inv, p2 = e2 * inv, p3 = e3 * inv;
        int bi = 0; float bp = p0;
        if (p1 > bp) { bp = p1; bi = 1; }
        if (p2 > bp) { bp = p2; bi = 2; }
        if (p3 > bp) { bp = p3; bi = 3; }
        if (lane == 0) {
            top_idx[tok]  = bi;
            top_prob[tok] = bp;
            atomicAdd(&s_cnt[bi], 1);
        }
        if (lane < NE) {
            float pv = (lane == 0) ? p0 : (lane == 1) ? p1 : (lane == 2) ? p2 : p3;
            atomicAdd(&s_imp[lane], pv);
        }
        __syncthreads();
    }
    if (tid < NE) {
        atomicAdd(&importance[tid], s_imp[tid]);
        atomicAdd(&counts[tid], s_cnt[tid]);
    }
}

// ---------------------------------------------------------------------------
// Kernel 2: exclusive scan of the 4 counts + load-balance loss.
// ---------------------------------------------------------------------------
__global__ void scan_lb_kernel(const int* __restrict__ counts,
                               const float* __restrict__ importance,
                               int* __restrict__ offsets,
                               float* __restrict__ d_out_lb)
{
    int c0 = counts[0], c1 = counts[1], c2 = counts[2], c3 = counts[3];
    offsets[0] = 0;
    offsets[1] = c0;
    offsets[2] = c0 + c1;
    offsets[3] = c0 + c1 + c2;
    double num = (double)importance[0] * c0 + (double)importance[1] * c1 +
                 (double)importance[2] * c2 + (double)importance[3] * c3;
    double lb = (double)NE * num / ((double)N_TOK * (double)N_TOK + 1e-8);
    *d_out_lb = (float)lb;
}

// ---------------------------------------------------------------------------
// Kernel 3: bucket tokens by expert.
// ---------------------------------------------------------------------------
__global__ __launch_bounds__(256) void place_kernel(
    const int* __restrict__ top_idx, const int* __restrict__ offsets,
    int* __restrict__ cursors, int* __restrict__ order)
{
    __shared__ int lcnt[NE];
    __shared__ int lbase[NE];
    const int tid = threadIdx.x;
    const int i   = blockIdx.x * 256 + tid;
    if (tid < NE) lcnt[tid] = 0;
    __syncthreads();
    const int e = top_idx[i];
    const int r = atomicAdd(&lcnt[e], 1);
    __syncthreads();
    if (tid < NE) lbase[tid] = (lcnt[tid] > 0) ? atomicAdd(&cursors[tid], lcnt[tid]) : 0;
    __syncthreads();
    order[offsets[e] + lbase[e] + r] = i;
}

// ---------------------------------------------------------------------------
// Kernel 4: MFMA expert FFN. 32 tokens/block, 4 waves split N.
// L1: [32,256]@[256,512] (wave owns 128 cols)  L2: [32,512]@[512,256] (64 cols)
// ---------------------------------------------------------------------------
__global__ __launch_bounds__(256, 2) void expert_mfma_kernel(
    const float* __restrict__ h,
    const unsigned short* __restrict__ w1t,  // [E][FF][HD] bf16
    const unsigned short* __restrict__ w2t,  // [E][HD][FF] bf16
    const float* __restrict__ b1, const float* __restrict__ b2,
    const float* __restrict__ top_prob,
    const int* __restrict__ order, const int* __restrict__ counts,
    const int* __restrict__ offsets, float* __restrict__ out)
{
    __shared__ float          sh_h[MT][260];  // fp32, padded
    __shared__ unsigned short sh_a[MT][520];  // bf16, padded
    __shared__ int            s_tok[MT];

    const int tid = threadIdx.x;

    int c = blockIdx.x, e;
    for (e = 0; e < NE; ++e) {
        int nch = (counts[e] + MT - 1) / MT;
        if (c < nch) break;
        c -= nch;
    }
    if (e >= NE) return;
    const int cnt  = counts[e];
    const int base = offsets[e] + c * MT;
    const int nt   = min(MT, cnt - c * MT);

    if (tid < MT) s_tok[tid] = (tid < nt) ? order[base + tid] : -1;
    __syncthreads();

    // gather h rows (fp32) -> LDS
    #pragma unroll
    for (int it = 0; it < 8; ++it) {
        int idx = tid + it * 256;          // 2048 float4 slots
        int r = idx >> 6, q = idx & 63;
        int t = s_tok[r];
        float4 val = make_float4(0.f, 0.f, 0.f, 0.f);
        if (t >= 0) val = *reinterpret_cast<const float4*>(&h[(size_t)t * HD + q * 4]);
        *reinterpret_cast<float4*>(&sh_h[r][q * 4]) = val;
    }
    __syncthreads();

    const int lane = tid & 63;
    const int wv   = tid >> 6;
    const int row  = lane & 15;   // M-row / N-col within fragment
    const int kg   = lane >> 4;   // k-group

    // ================= layer 1: wave owns cols [wv*128, wv*128+128) ========
    const unsigned short* W1 = w1t + (size_t)e * FF * HD;
    f32x4 acc1[2][8];
    #pragma unroll
    for (int ni = 0; ni < 8; ++ni) {
        float bb = b1[e * FF + wv * 128 + ni * 16 + row];
        #pragma unroll
        for (int mi = 0; mi < 2; ++mi)
            acc1[mi][ni] = (f32x4){bb, bb, bb, bb};
    }
    #pragma unroll 2
    for (int ks = 0; ks < HD / 32; ++ks) {
        short8 a[2];
        #pragma unroll
        for (int mi = 0; mi < 2; ++mi) {
            const float* p = &sh_h[mi * 16 + row][ks * 32 + kg * 8];
            f32x4 f0 = *reinterpret_cast<const f32x4*>(p);
            f32x4 f1 = *reinterpret_cast<const f32x4*>(p + 4);
            short8 t;
            t[0] = (short)f2bf(f0[0]); t[1] = (short)f2bf(f0[1]);
            t[2] = (short)f2bf(f0[2]); t[3] = (short)f2bf(f0[3]);
            t[4] = (short)f2bf(f1[0]); t[5] = (short)f2bf(f1[1]);
            t[6] = (short)f2bf(f1[2]); t[7] = (short)f2bf(f1[3]);
            a[mi] = t;
        }
        #pragma unroll
        for (int ni = 0; ni < 8; ++ni) {
            const unsigned short* bp =
                W1 + (size_t)(wv * 128 + ni * 16 + row) * HD + ks * 32 + kg * 8;
            short8 b = *reinterpret_cast<const short8*>(bp);
            acc1[0][ni] = __builtin_amdgcn_mfma_f32_16x16x32_bf16(a[0], b, acc1[0][ni], 0, 0, 0);
            acc1[1][ni] = __builtin_amdgcn_mfma_f32_16x16x32_bf16(a[1], b, acc1[1][ni], 0, 0, 0);
        }
    }
    // gelu -> bf16 act tile
    #pragma unroll
    for (int mi = 0; mi < 2; ++mi)
        #pragma unroll
        for (int ni = 0; ni < 8; ++ni)
            #pragma unroll
            for (int r = 0; r < 4; ++r) {
                int tr = mi * 16 + kg * 4 + r;
                int cl = wv * 128 + ni * 16 + row;
                sh_a[tr][cl] = f2bf(gelu_f(acc1[mi][ni][r]));
            }
    __syncthreads();

    // ================= layer 2: wave owns out cols [wv*64, wv*64+64) =======
    const unsigned short* W2 = w2t + (size_t)e * HD * FF;
    f32x4 acc2[2][4];
    #pragma unroll
    for (int ni = 0; ni < 4; ++ni) {
        float bb = b2[e * HD + wv * 64 + ni * 16 + row];
        #pragma unroll
        for (int mi = 0; mi < 2; ++mi)
            acc2[mi][ni] = (f32x4){bb, bb, bb, bb};
    }
    #pragma unroll 2
    for (int ks = 0; ks < FF / 32; ++ks) {
        short8 a2[2];
        #pragma unroll
        for (int mi = 0; mi < 2; ++mi)
            a2[mi] = *reinterpret_cast<const short8*>(&sh_a[mi * 16 + row][ks * 32 + kg * 8]);
        #pragma unroll
        for (int ni = 0; ni < 4; ++ni) {
            const unsigned short* bp =
                W2 + (size_t)(wv * 64 + ni * 16 + row) * FF + ks * 32 + kg * 8;
            short8 b = *reinterpret_cast<const short8*>(bp);
            acc2[0][ni] = __builtin_amdgcn_mfma_f32_16x16x32_bf16(a2[0], b, acc2[0][ni], 0, 0, 0);
            acc2[1][ni] = __builtin_amdgcn_mfma_f32_16x16x32_bf16(a2[1], b, acc2[1][ni], 0, 0, 0);
        }
    }

    // epilogue: out = h + 0.5 * top_prob * y   (h fp32 from LDS, exact)
    int   gtok[2][4];
    float tpr[2][4];
    #pragma unroll
    for (int mi = 0; mi < 2; ++mi)
        #pragma unroll
        for (int r = 0; r < 4; ++r) {
            int tr = mi * 16 + kg * 4 + r;
            int gt = s_tok[tr];
            gtok[mi][r] = gt;
            tpr[mi][r]  = (gt >= 0) ? 0.5f * top_prob[gt] : 0.f;
        }
    #pragma unroll
    for (int mi = 0; mi < 2; ++mi)
        #pragma unroll
        for (int ni = 0; ni < 4; ++ni)
            #pragma unroll
            for (int r = 0; r < 4; ++r) {
                int gt = gtok[mi][r];
                if (gt < 0) continue;
                int tr = mi * 16 + kg * 4 + r;
                int cl = wv * 64 + ni * 16 + row;
                float res = sh_h[tr][cl];
                out[(size_t)gt * HD + cl] = res + tpr[mi][r] * acc2[mi][ni][r];
            }
}

// ---------------------------------------------------------------------------
extern "C" void kernel_launch(void* const* d_in, const int* in_sizes, int n_in,
                              void* d_out, int out_size, void* d_ws, size_t ws_size,
                              hipStream_t stream)
{
    const float* h        = (const float*)d_in[0];
    const float* tok_emb  = (const float*)d_in[1];
    /* d_in[2] = is_mask: all zeros, unused by the reference math */
    const float* ln_g     = (const float*)d_in[3];
    const float* ln_b     = (const float*)d_in[4];
    const float* geom_w   = (const float*)d_in[5];
    const float* geom_b   = (const float*)d_in[6];
    const float* fuse_w   = (const float*)d_in[7];
    const float* fuse_b   = (const float*)d_in[8];
    const float* router_w = (const float*)d_in[9];
    const float* router_b = (const float*)d_in[10];
    const float* w1       = (const float*)d_in[11];
    const float* b1       = (const float*)d_in[12];
    const float* w2       = (const float*)d_in[13];
    const float* b2       = (const float*)d_in[14];
    float* out = (float*)d_out;

    // workspace layout (4B units)
    int*   counts     = (int*)d_ws;                   // [4]
    float* importance = (float*)d_ws + 4;             // [4]
    int*   offsets    = (int*)d_ws + 8;               // [4]
    int*   cursors    = (int*)d_ws + 12;              // [4]
    int*   top_idx    = (int*)d_ws + 64;              // [N]
    float* top_prob   = (float*)d_ws + 64 + N_TOK;    // [N]
    int*   order      = (int*)d_ws + 64 + 2 * N_TOK;  // [N]
    unsigned short* w1t = (unsigned short*)((int*)d_ws + 64 + 3 * N_TOK); // 1MB
    unsigned short* w2t = w1t + (size_t)NE * FF * HD;                     // 1MB

    hipMemsetAsync(d_ws, 0, 64 * sizeof(int), stream);

    prep_weights_kernel<<<1024, 256, 0, stream>>>(w1, w2, w1t, w2t);

    router_kernel<<<N_TOK / 64, 256, 0, stream>>>(
        h, tok_emb, ln_g, ln_b, geom_w, geom_b, fuse_w, fuse_b,
        router_w, router_b, top_idx, top_prob, counts, importance);

    scan_lb_kernel<<<1, 1, 0, stream>>>(counts, importance, offsets,
                                        &out[(size_t)N_TOK * HD]);

    place_kernel<<<N_TOK / 256, 256, 0, stream>>>(top_idx, offsets, cursors, order);

    expert_mfma_kernel<<<N_TOK / MT + NE, 256, 0, stream>>>(
        h, w1t, w2t, b1, b2, top_prob, order, counts, offsets, out);
}

// Round 3
// 562.185 us; speedup vs baseline: 3.4527x; 1.1249x over previous
//
#include <hip/hip_runtime.h>
#include <hip/hip_bf16.h>
#include <math.h>

#define N_TOK 131072
#define HD    256
#define DS    32
#define DG    32
#define FM    64
#define NE    4
#define FF    512
#define MT    32   // tokens per expert block

typedef short  short8 __attribute__((ext_vector_type(8)));
typedef float  f32x4  __attribute__((ext_vector_type(4)));

__device__ __forceinline__ float gelu_f(float x) {
    return 0.5f * x * (1.0f + erff(x * 0.70710678118654752f));
}
__device__ __forceinline__ unsigned short f2bf(float x) {
    union { __hip_bfloat16 b; unsigned short u; } cv;
    cv.b = __float2bfloat16(x);
    return cv.u;
}

// ---------------------------------------------------------------------------
// Prep: transpose+convert w1 [E][K][N]->w1t [E][N][K] bf16, w2 likewise.
// ---------------------------------------------------------------------------
__global__ __launch_bounds__(256) void prep_weights_kernel(
    const float* __restrict__ w1, const float* __restrict__ w2,
    unsigned short* __restrict__ w1t, unsigned short* __restrict__ w2t)
{
    __shared__ float tile[32][33];
    int b = blockIdx.x;
    const float* src; unsigned short* dst; int K, Nn;
    if (b < 512) { int e = b >> 7; int t = b & 127;
        src = w1 + (size_t)e * HD * FF; dst = w1t + (size_t)e * HD * FF;
        K = HD; Nn = FF; b = t;
    } else { b -= 512; int e = b >> 7; int t = b & 127;
        src = w2 + (size_t)e * FF * HD; dst = w2t + (size_t)e * FF * HD;
        K = FF; Nn = HD; b = t;
    }
    int ntn = Nn / 32;
    int kt = b / ntn, nt = b % ntn;
    int r = threadIdx.x >> 3, c4 = threadIdx.x & 7;
    float4 v = *reinterpret_cast<const float4*>(&src[(size_t)(kt*32 + r) * Nn + nt*32 + c4*4]);
    tile[r][c4*4+0] = v.x; tile[r][c4*4+1] = v.y;
    tile[r][c4*4+2] = v.z; tile[r][c4*4+3] = v.w;
    __syncthreads();
    ushort4 o;
    o.x = f2bf(tile[c4*4+0][r]); o.y = f2bf(tile[c4*4+1][r]);
    o.z = f2bf(tile[c4*4+2][r]); o.w = f2bf(tile[c4*4+3][r]);
    *reinterpret_cast<ushort4*>(&dst[(size_t)(nt*32 + r) * K + kt*32 + c4*4]) = o;
}

// ---------------------------------------------------------------------------
// Router: 64 tokens/block, weights staged in LDS, fp32, NO intra-loop
// barriers (all LDS buffers are wave-private), next-token prefetch.
// ---------------------------------------------------------------------------
__global__ __launch_bounds__(256) void router_kernel(
    const float* __restrict__ h, const float* __restrict__ tok_emb,
    const float* __restrict__ ln_g, const float* __restrict__ ln_b,
    const float* __restrict__ geom_w, const float* __restrict__ geom_b,
    const float* __restrict__ fuse_w, const float* __restrict__ fuse_b,
    const float* __restrict__ router_w, const float* __restrict__ router_b,
    int* __restrict__ top_idx, float* __restrict__ top_prob,
    int* __restrict__ counts, float* __restrict__ importance)
{
    __shared__ float wg[HD * DG];       // 32 KB
    __shared__ float wf[(DS+DG) * FM];  // 16 KB
    __shared__ float wr[FM * NE];       // 1 KB
    __shared__ float sh_ln[4][HD];
    __shared__ float sh_c[4][DS + DG];
    __shared__ float sh_u[4][FM];
    __shared__ float s_imp[NE];
    __shared__ int   s_cnt[NE];

    const int tid  = threadIdx.x;
    const int wv   = tid >> 6;
    const int lane = tid & 63;

    for (int i = tid; i < HD * DG / 4; i += 256)
        reinterpret_cast<float4*>(wg)[i] = reinterpret_cast<const float4*>(geom_w)[i];
    for (int i = tid; i < (DS+DG) * FM / 4; i += 256)
        reinterpret_cast<float4*>(wf)[i] = reinterpret_cast<const float4*>(fuse_w)[i];
    if (tid < FM * NE) wr[tid] = router_w[tid];
    if (tid < NE) { s_imp[tid] = 0.f; s_cnt[tid] = 0; }

    const float4 rb = *reinterpret_cast<const float4*>(router_b);
    float4 g4 = *reinterpret_cast<const float4*>(&ln_g[lane * 4]);
    float4 b4 = *reinterpret_cast<const float4*>(&ln_b[lane * 4]);
    __syncthreads();

    const int base = blockIdx.x * 64 + wv * 16;
    float4 hv = *reinterpret_cast<const float4*>(&h[(size_t)base * HD + lane * 4]);
    float  te = (lane < DS) ? tok_emb[(size_t)base * DS + lane] : 0.f;

    for (int ti = 0; ti < 16; ++ti) {
        const int tok = base + ti;
        // ---- LayerNorm (register/shuffle) ----
        float s = hv.x + hv.y + hv.z + hv.w;
        #pragma unroll
        for (int off = 32; off; off >>= 1) s += __shfl_xor(s, off);
        float mu = s * (1.0f / HD);
        float d0 = hv.x - mu, d1 = hv.y - mu, d2 = hv.z - mu, d3 = hv.w - mu;
        float v = d0*d0 + d1*d1 + d2*d2 + d3*d3;
        #pragma unroll
        for (int off = 32; off; off >>= 1) v += __shfl_xor(v, off);
        float rstd = rsqrtf(v * (1.0f / HD) + 1e-5f);
        float4 ln;
        ln.x = d0 * rstd * g4.x + b4.x;
        ln.y = d1 * rstd * g4.y + b4.y;
        ln.z = d2 * rstd * g4.z + b4.z;
        ln.w = d3 * rstd * g4.w + b4.w;
        *reinterpret_cast<float4*>(&sh_ln[wv][lane * 4]) = ln;
        if (lane < DS) sh_c[wv][lane] = te;

        // prefetch next token
        if (ti < 15) {
            hv = *reinterpret_cast<const float4*>(&h[(size_t)(tok + 1) * HD + lane * 4]);
            if (lane < DS) te = tok_emb[(size_t)(tok + 1) * DS + lane];
        }

        // ---- geom ----
        {
            const int j = lane & 31, half = lane >> 5;
            const float* hl = sh_ln[wv];
            float a0 = 0.f, a1 = 0.f, a2 = 0.f, a3 = 0.f;
            const int k0 = half * 128;
            #pragma unroll 8
            for (int k = k0; k < k0 + 128; k += 4) {
                a0 = fmaf(hl[k+0], wg[(k+0)*DG + j], a0);
                a1 = fmaf(hl[k+1], wg[(k+1)*DG + j], a1);
                a2 = fmaf(hl[k+2], wg[(k+2)*DG + j], a2);
                a3 = fmaf(hl[k+3], wg[(k+3)*DG + j], a3);
            }
            float acc = (a0 + a1) + (a2 + a3);
            acc += __shfl_xor(acc, 32);
            if (half == 0) sh_c[wv][DS + j] = gelu_f(acc + geom_b[j]);
        }

        // ---- fuse ----
        {
            const float* c = sh_c[wv];
            float a0 = 0.f, a1 = 0.f, a2 = 0.f, a3 = 0.f;
            #pragma unroll 4
            for (int k = 0; k < DS + DG; k += 4) {
                a0 = fmaf(c[k+0], wf[(k+0)*FM + lane], a0);
                a1 = fmaf(c[k+1], wf[(k+1)*FM + lane], a1);
                a2 = fmaf(c[k+2], wf[(k+2)*FM + lane], a2);
                a3 = fmaf(c[k+3], wf[(k+3)*FM + lane], a3);
            }
            sh_u[wv][lane] = gelu_f(((a0 + a1) + (a2 + a3)) + fuse_b[lane]);
        }

        // ---- logits: lane = (expert, k-chunk) ----
        const int ee = lane >> 4, kk = lane & 15;
        float pp = 0.f;
        #pragma unroll
        for (int i = 0; i < 4; ++i) {
            int k = kk * 4 + i;
            pp = fmaf(sh_u[wv][k], wr[k * NE + ee], pp);
        }
        pp += __shfl_xor(pp, 1);
        pp += __shfl_xor(pp, 2);
        pp += __shfl_xor(pp, 4);
        pp += __shfl_xor(pp, 8);
        float l0 = __shfl(pp, 0)  + rb.x;
        float l1 = __shfl(pp, 16) + rb.y;
        float l2 = __shfl(pp, 32) + rb.z;
        float l3 = __shfl(pp, 48) + rb.w;
        float m  = fmaxf(fmaxf(l0, l1), fmaxf(l2, l3));
        float e0 = expf(l0 - m), e1 = expf(l1 - m), e2 = expf(l2 - m), e3 = expf(l3 - m);
        float inv = 1.0f / (e0 + e1 + e2 + e3);
        float p0 = e0 * inv, p1 = e1 * inv, p2 = e2 * inv, p3 = e3 * inv;
        int bi = 0; float bp = p0;
        if (p1 > bp) { bp = p1; bi = 1; }
        if (p2 > bp) { bp = p2; bi = 2; }
        if (p3 > bp) { bp = p3; bi = 3; }
        if (lane == 0) {
            top_idx[tok]  = bi;
            top_prob[tok] = bp;
            atomicAdd(&s_cnt[bi], 1);
        }
        if (lane < NE) {
            float pv = (lane == 0) ? p0 : (lane == 1) ? p1 : (lane == 2) ? p2 : p3;
            atomicAdd(&s_imp[lane], pv);
        }
    }
    __syncthreads();
    if (tid < NE) {
        atomicAdd(&importance[tid], s_imp[tid]);
        atomicAdd(&counts[tid], s_cnt[tid]);
    }
}

// ---------------------------------------------------------------------------
// Kernel 2: exclusive scan + load-balance loss.
// ---------------------------------------------------------------------------
__global__ void scan_lb_kernel(const int* __restrict__ counts,
                               const float* __restrict__ importance,
                               int* __restrict__ offsets,
                               float* __restrict__ d_out_lb)
{
    int c0 = counts[0], c1 = counts[1], c2 = counts[2], c3 = counts[3];
    offsets[0] = 0;
    offsets[1] = c0;
    offsets[2] = c0 + c1;
    offsets[3] = c0 + c1 + c2;
    double num = (double)importance[0] * c0 + (double)importance[1] * c1 +
                 (double)importance[2] * c2 + (double)importance[3] * c3;
    double lb = (double)NE * num / ((double)N_TOK * (double)N_TOK + 1e-8);
    *d_out_lb = (float)lb;
}

// ---------------------------------------------------------------------------
// Kernel 3: bucket tokens by expert.
// ---------------------------------------------------------------------------
__global__ __launch_bounds__(256) void place_kernel(
    const int* __restrict__ top_idx, const int* __restrict__ offsets,
    int* __restrict__ cursors, int* __restrict__ order)
{
    __shared__ int lcnt[NE];
    __shared__ int lbase[NE];
    const int tid = threadIdx.x;
    const int i   = blockIdx.x * 256 + tid;
    if (tid < NE) lcnt[tid] = 0;
    __syncthreads();
    const int e = top_idx[i];
    const int r = atomicAdd(&lcnt[e], 1);
    __syncthreads();
    if (tid < NE) lbase[tid] = (lcnt[tid] > 0) ? atomicAdd(&cursors[tid], lcnt[tid]) : 0;
    __syncthreads();
    order[offsets[e] + lbase[e] + r] = i;
}

// ---------------------------------------------------------------------------
// Kernel 4: MFMA expert FFN. 32 tokens/block, 4 waves split N.
// bf16 LDS staging (h and activations) -> 50 KB LDS -> 3 blocks/CU.
// Residual re-reads fp32 h from global (L3-resident).
// ---------------------------------------------------------------------------
__global__ __launch_bounds__(256, 3) void expert_mfma_kernel(
    const float* __restrict__ h,
    const unsigned short* __restrict__ w1t,  // [E][FF][HD] bf16
    const unsigned short* __restrict__ w2t,  // [E][HD][FF] bf16
    const float* __restrict__ b1, const float* __restrict__ b2,
    const float* __restrict__ top_prob,
    const int* __restrict__ order, const int* __restrict__ counts,
    const int* __restrict__ offsets, float* __restrict__ out)
{
    __shared__ __align__(16) unsigned short sh_h[MT][264];  // bf16, 16.9 KB
    __shared__ __align__(16) unsigned short sh_a[MT][520];  // bf16, 33.3 KB
    __shared__ int s_tok[MT];

    const int tid = threadIdx.x;

    int c = blockIdx.x, e;
    for (e = 0; e < NE; ++e) {
        int nch = (counts[e] + MT - 1) / MT;
        if (c < nch) break;
        c -= nch;
    }
    if (e >= NE) return;
    const int cnt  = counts[e];
    const int base = offsets[e] + c * MT;
    const int nt   = min(MT, cnt - c * MT);

    if (tid < MT) s_tok[tid] = (tid < nt) ? order[base + tid] : -1;
    __syncthreads();

    // gather h rows -> bf16 LDS (convert once)
    #pragma unroll
    for (int it = 0; it < 4; ++it) {
        int idx = tid + it * 256;           // 1024 slots of 8 floats
        int r = idx >> 5, q = idx & 31;
        int t = s_tok[r];
        float4 v0 = make_float4(0.f,0.f,0.f,0.f), v1 = v0;
        if (t >= 0) {
            const float* p = &h[(size_t)t * HD + q * 8];
            v0 = *reinterpret_cast<const float4*>(p);
            v1 = *reinterpret_cast<const float4*>(p + 4);
        }
        short8 o;
        o[0] = (short)f2bf(v0.x); o[1] = (short)f2bf(v0.y);
        o[2] = (short)f2bf(v0.z); o[3] = (short)f2bf(v0.w);
        o[4] = (short)f2bf(v1.x); o[5] = (short)f2bf(v1.y);
        o[6] = (short)f2bf(v1.z); o[7] = (short)f2bf(v1.w);
        *reinterpret_cast<short8*>(&sh_h[r][q * 8]) = o;
    }
    __syncthreads();

    const int lane = tid & 63;
    const int wv   = tid >> 6;
    const int row  = lane & 15;   // N-col (B/C) and M-row (A) index
    const int kg   = lane >> 4;   // k-group

    // ================= layer 1: wave owns cols [wv*128, wv*128+128) ========
    const unsigned short* W1 = w1t + (size_t)e * FF * HD
                             + (size_t)(wv * 128 + row) * HD + kg * 8;
    f32x4 acc1[2][8];
    #pragma unroll
    for (int ni = 0; ni < 8; ++ni) {
        float bb = b1[e * FF + wv * 128 + ni * 16 + row];
        acc1[0][ni] = (f32x4){bb, bb, bb, bb};
        acc1[1][ni] = (f32x4){bb, bb, bb, bb};
    }
    #pragma unroll
    for (int ks = 0; ks < HD / 32; ++ks) {
        short8 a[2];
        a[0] = *reinterpret_cast<const short8*>(&sh_h[row][ks * 32 + kg * 8]);
        a[1] = *reinterpret_cast<const short8*>(&sh_h[16 + row][ks * 32 + kg * 8]);
        #pragma unroll
        for (int ni = 0; ni < 8; ++ni) {
            short8 b = *reinterpret_cast<const short8*>(&W1[(size_t)ni * 16 * HD + ks * 32]);
            acc1[0][ni] = __builtin_amdgcn_mfma_f32_16x16x32_bf16(a[0], b, acc1[0][ni], 0, 0, 0);
            acc1[1][ni] = __builtin_amdgcn_mfma_f32_16x16x32_bf16(a[1], b, acc1[1][ni], 0, 0, 0);
        }
    }
    // gelu -> bf16 act tile
    #pragma unroll
    for (int mi = 0; mi < 2; ++mi)
        #pragma unroll
        for (int ni = 0; ni < 8; ++ni)
            #pragma unroll
            for (int r = 0; r < 4; ++r) {
                int tr = mi * 16 + kg * 4 + r;
                int cl = wv * 128 + ni * 16 + row;
                sh_a[tr][cl] = f2bf(gelu_f(acc1[mi][ni][r]));
            }
    __syncthreads();

    // ================= layer 2: wave owns out cols [wv*64, wv*64+64) =======
    const unsigned short* W2 = w2t + (size_t)e * HD * FF
                             + (size_t)(wv * 64 + row) * FF + kg * 8;
    f32x4 acc2[2][4];
    #pragma unroll
    for (int ni = 0; ni < 4; ++ni) {
        float bb = b2[e * HD + wv * 64 + ni * 16 + row];
        acc2[0][ni] = (f32x4){bb, bb, bb, bb};
        acc2[1][ni] = (f32x4){bb, bb, bb, bb};
    }
    #pragma unroll
    for (int ks = 0; ks < FF / 32; ++ks) {
        short8 a2[2];
        a2[0] = *reinterpret_cast<const short8*>(&sh_a[row][ks * 32 + kg * 8]);
        a2[1] = *reinterpret_cast<const short8*>(&sh_a[16 + row][ks * 32 + kg * 8]);
        #pragma unroll
        for (int ni = 0; ni < 4; ++ni) {
            short8 b = *reinterpret_cast<const short8*>(&W2[(size_t)ni * 16 * FF + ks * 32]);
            acc2[0][ni] = __builtin_amdgcn_mfma_f32_16x16x32_bf16(a2[0], b, acc2[0][ni], 0, 0, 0);
            acc2[1][ni] = __builtin_amdgcn_mfma_f32_16x16x32_bf16(a2[1], b, acc2[1][ni], 0, 0, 0);
        }
    }

    // epilogue: out = h + 0.5 * top_prob * y  (fp32 h from global, exact)
    int   gtok[2][4];
    float tpr[2][4];
    #pragma unroll
    for (int mi = 0; mi < 2; ++mi)
        #pragma unroll
        for (int r = 0; r < 4; ++r) {
            int tr = mi * 16 + kg * 4 + r;
            int gt = s_tok[tr];
            gtok[mi][r] = gt;
            tpr[mi][r]  = (gt >= 0) ? 0.5f * top_prob[gt] : 0.f;
        }
    #pragma unroll
    for (int mi = 0; mi < 2; ++mi)
        #pragma unroll
        for (int ni = 0; ni < 4; ++ni)
            #pragma unroll
            for (int r = 0; r < 4; ++r) {
                int gt = gtok[mi][r];
                if (gt < 0) continue;
                int cl = wv * 64 + ni * 16 + row;
                float res = h[(size_t)gt * HD + cl];
                out[(size_t)gt * HD + cl] = res + tpr[mi][r] * acc2[mi][ni][r];
            }
}

// ---------------------------------------------------------------------------
extern "C" void kernel_launch(void* const* d_in, const int* in_sizes, int n_in,
                              void* d_out, int out_size, void* d_ws, size_t ws_size,
                              hipStream_t stream)
{
    const float* h        = (const float*)d_in[0];
    const float* tok_emb  = (const float*)d_in[1];
    /* d_in[2] = is_mask: all zeros, unused by the reference math */
    const float* ln_g     = (const float*)d_in[3];
    const float* ln_b     = (const float*)d_in[4];
    const float* geom_w   = (const float*)d_in[5];
    const float* geom_b   = (const float*)d_in[6];
    const float* fuse_w   = (const float*)d_in[7];
    const float* fuse_b   = (const float*)d_in[8];
    const float* router_w = (const float*)d_in[9];
    const float* router_b = (const float*)d_in[10];
    const float* w1       = (const float*)d_in[11];
    const float* b1       = (const float*)d_in[12];
    const float* w2       = (const float*)d_in[13];
    const float* b2       = (const float*)d_in[14];
    float* out = (float*)d_out;

    // workspace layout (4B units)
    int*   counts     = (int*)d_ws;                   // [4]
    float* importance = (float*)d_ws + 4;             // [4]
    int*   offsets    = (int*)d_ws + 8;               // [4]
    int*   cursors    = (int*)d_ws + 12;              // [4]
    int*   top_idx    = (int*)d_ws + 64;              // [N]
    float* top_prob   = (float*)d_ws + 64 + N_TOK;    // [N]
    int*   order      = (int*)d_ws + 64 + 2 * N_TOK;  // [N]
    unsigned short* w1t = (unsigned short*)((int*)d_ws + 64 + 3 * N_TOK); // 1MB
    unsigned short* w2t = w1t + (size_t)NE * FF * HD;                     // 1MB

    hipMemsetAsync(d_ws, 0, 64 * sizeof(int), stream);

    prep_weights_kernel<<<1024, 256, 0, stream>>>(w1, w2, w1t, w2t);

    router_kernel<<<N_TOK / 64, 256, 0, stream>>>(
        h, tok_emb, ln_g, ln_b, geom_w, geom_b, fuse_w, fuse_b,
        router_w, router_b, top_idx, top_prob, counts, importance);

    scan_lb_kernel<<<1, 1, 0, stream>>>(counts, importance, offsets,
                                        &out[(size_t)N_TOK * HD]);

    place_kernel<<<N_TOK / 256, 256, 0, stream>>>(top_idx, offsets, cursors, order);

    expert_mfma_kernel<<<N_TOK / MT + NE, 256, 0, stream>>>(
        h, w1t, w2t, b1, b2, top_prob, order, counts, offsets, out);
}

// Round 4
// 444.336 us; speedup vs baseline: 4.3685x; 1.2652x over previous
//
#include <hip/hip_runtime.h>
#include <hip/hip_bf16.h>
#include <math.h>

#define N_TOK 131072
#define HD    256
#define DS    32
#define DG    32
#define FM    64
#define NE    4
#define FF    512
#define MT    64   // tokens per expert block (8 waves, 512 threads)

typedef short  short8 __attribute__((ext_vector_type(8)));
typedef float  f32x4  __attribute__((ext_vector_type(4)));

__device__ __forceinline__ float gelu_f(float x) {
    return 0.5f * x * (1.0f + erff(x * 0.70710678118654752f));
}
__device__ __forceinline__ unsigned short f2bf(float x) {
    union { __hip_bfloat16 b; unsigned short u; } cv;
    cv.b = __float2bfloat16(x);
    return cv.u;
}

// ---------------------------------------------------------------------------
// Prep: repack w1/w2 into MFMA-FRAGMENT-ORDERED bf16 layout so every
// B-fragment load in the expert kernel is 64 lanes x 16B CONTIGUOUS (1 KB).
//   w1p[((e*8 + ks)*32 + ni)*512 + lane*8 + j] = w1[e][ks*32+kg*8+j][ni*16+row]
//   w2p[((e*16+ ks)*16 + ni)*512 + lane*8 + j] = w2[e][ks*32+kg*8+j][ni*16+row]
// where lane = kg*16 + row.
// ---------------------------------------------------------------------------
__global__ __launch_bounds__(256) void prep_weights_kernel(
    const float* __restrict__ w1, const float* __restrict__ w2,
    unsigned short* __restrict__ w1p, unsigned short* __restrict__ w2p)
{
    int t = (blockIdx.x & 255) * 256 + threadIdx.x;   // 0..65535
    const int lane = t & 63;
    const int kg   = lane >> 4;
    const int row  = lane & 15;
    if (blockIdx.x < 256) {
        // w1: [E][HD=256 k][FF=512 n]
        const int ni = (t >> 6) & 31;
        const int ks = (t >> 11) & 7;
        const int e  = t >> 14;
        const int n  = ni * 16 + row;
        const int k0 = ks * 32 + kg * 8;
        short8 o;
        #pragma unroll
        for (int j = 0; j < 8; ++j)
            o[j] = (short)f2bf(w1[((size_t)e * HD + k0 + j) * FF + n]);
        *reinterpret_cast<short8*>(&w1p[(size_t)(((e*8 + ks)*32 + ni)*64 + lane) * 8]) = o;
    } else {
        // w2: [E][FF=512 k][HD=256 n]
        const int ni = (t >> 6) & 15;
        const int ks = (t >> 10) & 15;
        const int e  = t >> 14;
        const int n  = ni * 16 + row;
        const int k0 = ks * 32 + kg * 8;
        short8 o;
        #pragma unroll
        for (int j = 0; j < 8; ++j)
            o[j] = (short)f2bf(w2[((size_t)e * FF + k0 + j) * HD + n]);
        *reinterpret_cast<short8*>(&w2p[(size_t)(((e*16 + ks)*16 + ni)*64 + lane) * 8]) = o;
    }
}

// ---------------------------------------------------------------------------
// Router: 64 tokens/block, weights staged in LDS, fp32, wave-private buffers.
// ---------------------------------------------------------------------------
__global__ __launch_bounds__(256) void router_kernel(
    const float* __restrict__ h, const float* __restrict__ tok_emb,
    const float* __restrict__ ln_g, const float* __restrict__ ln_b,
    const float* __restrict__ geom_w, const float* __restrict__ geom_b,
    const float* __restrict__ fuse_w, const float* __restrict__ fuse_b,
    const float* __restrict__ router_w, const float* __restrict__ router_b,
    int* __restrict__ top_idx, float* __restrict__ top_prob,
    int* __restrict__ counts, float* __restrict__ importance)
{
    __shared__ float wg[HD * DG];       // 32 KB
    __shared__ float wf[(DS+DG) * FM];  // 16 KB
    __shared__ float wr[FM * NE];       // 1 KB
    __shared__ float sh_ln[4][HD];
    __shared__ float sh_c[4][DS + DG];
    __shared__ float sh_u[4][FM];
    __shared__ float s_imp[NE];
    __shared__ int   s_cnt[NE];

    const int tid  = threadIdx.x;
    const int wv   = tid >> 6;
    const int lane = tid & 63;

    for (int i = tid; i < HD * DG / 4; i += 256)
        reinterpret_cast<float4*>(wg)[i] = reinterpret_cast<const float4*>(geom_w)[i];
    for (int i = tid; i < (DS+DG) * FM / 4; i += 256)
        reinterpret_cast<float4*>(wf)[i] = reinterpret_cast<const float4*>(fuse_w)[i];
    if (tid < FM * NE) wr[tid] = router_w[tid];
    if (tid < NE) { s_imp[tid] = 0.f; s_cnt[tid] = 0; }

    const float4 rb = *reinterpret_cast<const float4*>(router_b);
    float4 g4 = *reinterpret_cast<const float4*>(&ln_g[lane * 4]);
    float4 b4 = *reinterpret_cast<const float4*>(&ln_b[lane * 4]);
    __syncthreads();

    const int base = blockIdx.x * 64 + wv * 16;
    float4 hv = *reinterpret_cast<const float4*>(&h[(size_t)base * HD + lane * 4]);
    float  te = (lane < DS) ? tok_emb[(size_t)base * DS + lane] : 0.f;

    for (int ti = 0; ti < 16; ++ti) {
        const int tok = base + ti;
        float s = hv.x + hv.y + hv.z + hv.w;
        #pragma unroll
        for (int off = 32; off; off >>= 1) s += __shfl_xor(s, off);
        float mu = s * (1.0f / HD);
        float d0 = hv.x - mu, d1 = hv.y - mu, d2 = hv.z - mu, d3 = hv.w - mu;
        float v = d0*d0 + d1*d1 + d2*d2 + d3*d3;
        #pragma unroll
        for (int off = 32; off; off >>= 1) v += __shfl_xor(v, off);
        float rstd = rsqrtf(v * (1.0f / HD) + 1e-5f);
        float4 ln;
        ln.x = d0 * rstd * g4.x + b4.x;
        ln.y = d1 * rstd * g4.y + b4.y;
        ln.z = d2 * rstd * g4.z + b4.z;
        ln.w = d3 * rstd * g4.w + b4.w;
        *reinterpret_cast<float4*>(&sh_ln[wv][lane * 4]) = ln;
        if (lane < DS) sh_c[wv][lane] = te;

        if (ti < 15) {
            hv = *reinterpret_cast<const float4*>(&h[(size_t)(tok + 1) * HD + lane * 4]);
            if (lane < DS) te = tok_emb[(size_t)(tok + 1) * DS + lane];
        }

        {
            const int j = lane & 31, half = lane >> 5;
            const float* hl = sh_ln[wv];
            float a0 = 0.f, a1 = 0.f, a2 = 0.f, a3 = 0.f;
            const int k0 = half * 128;
            #pragma unroll 8
            for (int k = k0; k < k0 + 128; k += 4) {
                a0 = fmaf(hl[k+0], wg[(k+0)*DG + j], a0);
                a1 = fmaf(hl[k+1], wg[(k+1)*DG + j], a1);
                a2 = fmaf(hl[k+2], wg[(k+2)*DG + j], a2);
                a3 = fmaf(hl[k+3], wg[(k+3)*DG + j], a3);
            }
            float acc = (a0 + a1) + (a2 + a3);
            acc += __shfl_xor(acc, 32);
            if (half == 0) sh_c[wv][DS + j] = gelu_f(acc + geom_b[j]);
        }

        {
            const float* c = sh_c[wv];
            float a0 = 0.f, a1 = 0.f, a2 = 0.f, a3 = 0.f;
            #pragma unroll 4
            for (int k = 0; k < DS + DG; k += 4) {
                a0 = fmaf(c[k+0], wf[(k+0)*FM + lane], a0);
                a1 = fmaf(c[k+1], wf[(k+1)*FM + lane], a1);
                a2 = fmaf(c[k+2], wf[(k+2)*FM + lane], a2);
                a3 = fmaf(c[k+3], wf[(k+3)*FM + lane], a3);
            }
            sh_u[wv][lane] = gelu_f(((a0 + a1) + (a2 + a3)) + fuse_b[lane]);
        }

        const int ee = lane >> 4, kk = lane & 15;
        float pp = 0.f;
        #pragma unroll
        for (int i = 0; i < 4; ++i) {
            int k = kk * 4 + i;
            pp = fmaf(sh_u[wv][k], wr[k * NE + ee], pp);
        }
        pp += __shfl_xor(pp, 1);
        pp += __shfl_xor(pp, 2);
        pp += __shfl_xor(pp, 4);
        pp += __shfl_xor(pp, 8);
        float l0 = __shfl(pp, 0)  + rb.x;
        float l1 = __shfl(pp, 16) + rb.y;
        float l2 = __shfl(pp, 32) + rb.z;
        float l3 = __shfl(pp, 48) + rb.w;
        float m  = fmaxf(fmaxf(l0, l1), fmaxf(l2, l3));
        float e0 = expf(l0 - m), e1 = expf(l1 - m), e2 = expf(l2 - m), e3 = expf(l3 - m);
        float inv = 1.0f / (e0 + e1 + e2 + e3);
        float p0 = e0 * inv, p1 = e1 * inv, p2 = e2 * inv, p3 = e3 * inv;
        int bi = 0; float bp = p0;
        if (p1 > bp) { bp = p1; bi = 1; }
        if (p2 > bp) { bp = p2; bi = 2; }
        if (p3 > bp) { bp = p3; bi = 3; }
        if (lane == 0) {
            top_idx[tok]  = bi;
            top_prob[tok] = bp;
            atomicAdd(&s_cnt[bi], 1);
        }
        if (lane < NE) {
            float pv = (lane == 0) ? p0 : (lane == 1) ? p1 : (lane == 2) ? p2 : p3;
            atomicAdd(&s_imp[lane], pv);
        }
    }
    __syncthreads();
    if (tid < NE) {
        atomicAdd(&importance[tid], s_imp[tid]);
        atomicAdd(&counts[tid], s_cnt[tid]);
    }
}

// ---------------------------------------------------------------------------
__global__ void scan_lb_kernel(const int* __restrict__ counts,
                               const float* __restrict__ importance,
                               int* __restrict__ offsets,
                               float* __restrict__ d_out_lb)
{
    int c0 = counts[0], c1 = counts[1], c2 = counts[2], c3 = counts[3];
    offsets[0] = 0;
    offsets[1] = c0;
    offsets[2] = c0 + c1;
    offsets[3] = c0 + c1 + c2;
    double num = (double)importance[0] * c0 + (double)importance[1] * c1 +
                 (double)importance[2] * c2 + (double)importance[3] * c3;
    double lb = (double)NE * num / ((double)N_TOK * (double)N_TOK + 1e-8);
    *d_out_lb = (float)lb;
}

// ---------------------------------------------------------------------------
__global__ __launch_bounds__(256) void place_kernel(
    const int* __restrict__ top_idx, const int* __restrict__ offsets,
    int* __restrict__ cursors, int* __restrict__ order)
{
    __shared__ int lcnt[NE];
    __shared__ int lbase[NE];
    const int tid = threadIdx.x;
    const int i   = blockIdx.x * 256 + tid;
    if (tid < NE) lcnt[tid] = 0;
    __syncthreads();
    const int e = top_idx[i];
    const int r = atomicAdd(&lcnt[e], 1);
    __syncthreads();
    if (tid < NE) lbase[tid] = (lcnt[tid] > 0) ? atomicAdd(&cursors[tid], lcnt[tid]) : 0;
    __syncthreads();
    order[offsets[e] + lbase[e] + r] = i;
}

// ---------------------------------------------------------------------------
// Expert FFN: 64 tokens/block, 8 waves (512 thr), fragment-ordered LDS + B.
// L1: [64,256]@[256,512], wave owns 64 N-cols. L2: [64,512]@[512,256], 32 cols.
// All B-loads are 1KB-contiguous; all A ds_reads are conflict-free b128.
// ---------------------------------------------------------------------------
__global__ __launch_bounds__(512, 2) void expert_mfma_kernel(
    const float* __restrict__ h,
    const unsigned short* __restrict__ w1p,  // frag-ordered bf16
    const unsigned short* __restrict__ w2p,  // frag-ordered bf16
    const float* __restrict__ b1, const float* __restrict__ b2,
    const float* __restrict__ top_prob,
    const int* __restrict__ order, const int* __restrict__ counts,
    const int* __restrict__ offsets, float* __restrict__ out)
{
    __shared__ __align__(16) unsigned short sh_h[8 * 4 * 512];   // 32 KB [ks][mi][lane*8]
    __shared__ __align__(16) unsigned short sh_a[16 * 4 * 512];  // 64 KB [ks2][mi][lane*8]
    __shared__ int s_tok[MT];

    const int tid = threadIdx.x;

    int c = blockIdx.x, e;
    for (e = 0; e < NE; ++e) {
        int nch = (counts[e] + MT - 1) / MT;
        if (c < nch) break;
        c -= nch;
    }
    if (e >= NE) return;
    const int cnt  = counts[e];
    const int base = offsets[e] + c * MT;
    const int nt   = min(MT, cnt - c * MT);

    if (tid < MT) s_tok[tid] = (tid < nt) ? order[base + tid] : -1;
    __syncthreads();

    // gather h rows -> frag-ordered bf16 LDS
    #pragma unroll
    for (int it = 0; it < 4; ++it) {
        int chunk = tid + it * 512;        // 2048 chunks of 8 floats
        int tr = chunk >> 5, q = chunk & 31;
        int t = s_tok[tr];
        float4 v0 = make_float4(0.f,0.f,0.f,0.f), v1 = v0;
        if (t >= 0) {
            const float* p = &h[(size_t)t * HD + q * 8];
            v0 = *reinterpret_cast<const float4*>(p);
            v1 = *reinterpret_cast<const float4*>(p + 4);
        }
        short8 o;
        o[0] = (short)f2bf(v0.x); o[1] = (short)f2bf(v0.y);
        o[2] = (short)f2bf(v0.z); o[3] = (short)f2bf(v0.w);
        o[4] = (short)f2bf(v1.x); o[5] = (short)f2bf(v1.y);
        o[6] = (short)f2bf(v1.z); o[7] = (short)f2bf(v1.w);
        int ks = q >> 2, kg = q & 3, mi = tr >> 4, row = tr & 15;
        *reinterpret_cast<short8*>(&sh_h[((ks*4 + mi)*64 + kg*16 + row) * 8]) = o;
    }
    __syncthreads();

    const int lane  = tid & 63;
    const int wv    = tid >> 6;       // 0..7
    const int row15 = lane & 15;
    const int kg    = lane >> 4;

    // ================= layer 1: wave owns N-cols [wv*64, wv*64+64) =========
    const unsigned short* W1 = w1p + (size_t)e * 8 * 32 * 512;
    f32x4 acc1[4][4];
    #pragma unroll
    for (int ni = 0; ni < 4; ++ni) {
        float bb = b1[e * FF + wv * 64 + ni * 16 + row15];
        #pragma unroll
        for (int mi = 0; mi < 4; ++mi) acc1[mi][ni] = (f32x4){bb, bb, bb, bb};
    }
    #pragma unroll
    for (int ks = 0; ks < 8; ++ks) {
        short8 a[4];
        #pragma unroll
        for (int mi = 0; mi < 4; ++mi)
            a[mi] = *reinterpret_cast<const short8*>(&sh_h[((ks*4 + mi)*64 + lane) * 8]);
        #pragma unroll
        for (int ni = 0; ni < 4; ++ni) {
            short8 b = *reinterpret_cast<const short8*>(
                &W1[(size_t)((ks*32 + wv*4 + ni)*64 + lane) * 8]);
            #pragma unroll
            for (int mi = 0; mi < 4; ++mi)
                acc1[mi][ni] = __builtin_amdgcn_mfma_f32_16x16x32_bf16(a[mi], b, acc1[mi][ni], 0, 0, 0);
        }
    }
    // gelu -> frag-ordered bf16 act tile
    #pragma unroll
    for (int ni = 0; ni < 4; ++ni) {
        int ffl = ni * 16 + row15;              // 0..63 within wave's cols
        int ks2 = (wv * 64 + ffl) >> 5;
        int kgp = (ffl >> 3) & 3;
        int e8  = ffl & 7;
        #pragma unroll
        for (int mi = 0; mi < 4; ++mi)
            #pragma unroll
            for (int r = 0; r < 4; ++r) {
                int rowp = kg * 4 + r;
                sh_a[((ks2*4 + mi)*64 + kgp*16 + rowp) * 8 + e8] =
                    f2bf(gelu_f(acc1[mi][ni][r]));
            }
    }
    __syncthreads();

    // ================= layer 2: wave owns out-cols [wv*32, wv*32+32) =======
    const unsigned short* W2 = w2p + (size_t)e * 16 * 16 * 512;
    f32x4 acc2[4][2];
    #pragma unroll
    for (int ni = 0; ni < 2; ++ni) {
        float bb = b2[e * HD + wv * 32 + ni * 16 + row15];
        #pragma unroll
        for (int mi = 0; mi < 4; ++mi) acc2[mi][ni] = (f32x4){bb, bb, bb, bb};
    }
    #pragma unroll
    for (int ks = 0; ks < 16; ++ks) {
        short8 a2[4];
        #pragma unroll
        for (int mi = 0; mi < 4; ++mi)
            a2[mi] = *reinterpret_cast<const short8*>(&sh_a[((ks*4 + mi)*64 + lane) * 8]);
        #pragma unroll
        for (int ni = 0; ni < 2; ++ni) {
            short8 b = *reinterpret_cast<const short8*>(
                &W2[(size_t)((ks*16 + wv*2 + ni)*64 + lane) * 8]);
            #pragma unroll
            for (int mi = 0; mi < 4; ++mi)
                acc2[mi][ni] = __builtin_amdgcn_mfma_f32_16x16x32_bf16(a2[mi], b, acc2[mi][ni], 0, 0, 0);
        }
    }

    // epilogue: out = h + 0.5 * top_prob * y  (fp32 h re-read, L3-resident)
    #pragma unroll
    for (int mi = 0; mi < 4; ++mi)
        #pragma unroll
        for (int r = 0; r < 4; ++r) {
            int gt = s_tok[mi * 16 + kg * 4 + r];
            if (gt < 0) continue;
            float tp = 0.5f * top_prob[gt];
            #pragma unroll
            for (int ni = 0; ni < 2; ++ni) {
                int cl = wv * 32 + ni * 16 + row15;
                float res = h[(size_t)gt * HD + cl];
                out[(size_t)gt * HD + cl] = res + tp * acc2[mi][ni][r];
            }
        }
}

// ---------------------------------------------------------------------------
extern "C" void kernel_launch(void* const* d_in, const int* in_sizes, int n_in,
                              void* d_out, int out_size, void* d_ws, size_t ws_size,
                              hipStream_t stream)
{
    const float* h        = (const float*)d_in[0];
    const float* tok_emb  = (const float*)d_in[1];
    /* d_in[2] = is_mask: all zeros, unused by the reference math */
    const float* ln_g     = (const float*)d_in[3];
    const float* ln_b     = (const float*)d_in[4];
    const float* geom_w   = (const float*)d_in[5];
    const float* geom_b   = (const float*)d_in[6];
    const float* fuse_w   = (const float*)d_in[7];
    const float* fuse_b   = (const float*)d_in[8];
    const float* router_w = (const float*)d_in[9];
    const float* router_b = (const float*)d_in[10];
    const float* w1       = (const float*)d_in[11];
    const float* b1       = (const float*)d_in[12];
    const float* w2       = (const float*)d_in[13];
    const float* b2       = (const float*)d_in[14];
    float* out = (float*)d_out;

    // workspace layout (4B units)
    int*   counts     = (int*)d_ws;                   // [4]
    float* importance = (float*)d_ws + 4;             // [4]
    int*   offsets    = (int*)d_ws + 8;               // [4]
    int*   cursors    = (int*)d_ws + 12;              // [4]
    int*   top_idx    = (int*)d_ws + 64;              // [N]
    float* top_prob   = (float*)d_ws + 64 + N_TOK;    // [N]
    int*   order      = (int*)d_ws + 64 + 2 * N_TOK;  // [N]
    unsigned short* w1p = (unsigned short*)((int*)d_ws + 64 + 3 * N_TOK); // 1MB
    unsigned short* w2p = w1p + (size_t)NE * FF * HD;                     // 1MB

    hipMemsetAsync(d_ws, 0, 64 * sizeof(int), stream);

    prep_weights_kernel<<<512, 256, 0, stream>>>(w1, w2, w1p, w2p);

    router_kernel<<<N_TOK / 64, 256, 0, stream>>>(
        h, tok_emb, ln_g, ln_b, geom_w, geom_b, fuse_w, fuse_b,
        router_w, router_b, top_idx, top_prob, counts, importance);

    scan_lb_kernel<<<1, 1, 0, stream>>>(counts, importance, offsets,
                                        &out[(size_t)N_TOK * HD]);

    place_kernel<<<N_TOK / 256, 256, 0, stream>>>(top_idx, offsets, cursors, order);

    expert_mfma_kernel<<<N_TOK / MT + NE, 512, 0, stream>>>(
        h, w1p, w2p, b1, b2, top_prob, order, counts, offsets, out);
}

// Round 6
// 315.605 us; speedup vs baseline: 6.1503x; 1.4079x over previous
//
#include <hip/hip_runtime.h>
#include <hip/hip_bf16.h>
#include <math.h>

#define N_TOK 131072
#define HD    256
#define DS    32
#define DG    32
#define FM    64
#define NE    4
#define FF    512
#define MT    64   // tokens per expert block (8 waves, 512 threads)

typedef short    short8 __attribute__((ext_vector_type(8)));
typedef _Float16 f16x8  __attribute__((ext_vector_type(8)));
typedef float    f32x4  __attribute__((ext_vector_type(4)));

struct F16Pair { _Float16 hi, lo; };

__device__ __forceinline__ float gelu_f(float x) {
    return 0.5f * x * (1.0f + erff(x * 0.70710678118654752f));
}
__device__ __forceinline__ unsigned short f2bf(float x) {
    union { __hip_bfloat16 b; unsigned short u; } cv;
    cv.b = __float2bfloat16(x);
    return cv.u;
}
__device__ __forceinline__ F16Pair split16(float v) {
    F16Pair p;
    p.hi = (_Float16)v;
    p.lo = (_Float16)(v - (float)p.hi);
    return p;
}

// ---------------------------------------------------------------------------
// Prep A: expert weights -> MFMA-fragment-ordered bf16 (unchanged, verified).
// ---------------------------------------------------------------------------
__global__ __launch_bounds__(256) void prep_weights_kernel(
    const float* __restrict__ w1, const float* __restrict__ w2,
    unsigned short* __restrict__ w1p, unsigned short* __restrict__ w2p)
{
    int t = (blockIdx.x & 255) * 256 + threadIdx.x;
    const int lane = t & 63;
    const int kg   = lane >> 4;
    const int row  = lane & 15;
    if (blockIdx.x < 256) {
        const int ni = (t >> 6) & 31;
        const int ks = (t >> 11) & 7;
        const int e  = t >> 14;
        const int n  = ni * 16 + row;
        const int k0 = ks * 32 + kg * 8;
        short8 o;
        #pragma unroll
        for (int j = 0; j < 8; ++j)
            o[j] = (short)f2bf(w1[((size_t)e * HD + k0 + j) * FF + n]);
        *reinterpret_cast<short8*>(&w1p[(size_t)(((e*8 + ks)*32 + ni)*64 + lane) * 8]) = o;
    } else {
        const int ni = (t >> 6) & 15;
        const int ks = (t >> 10) & 15;
        const int e  = t >> 14;
        const int n  = ni * 16 + row;
        const int k0 = ks * 32 + kg * 8;
        short8 o;
        #pragma unroll
        for (int j = 0; j < 8; ++j)
            o[j] = (short)f2bf(w2[((size_t)e * FF + k0 + j) * HD + n]);
        *reinterpret_cast<short8*>(&w2p[(size_t)(((e*16 + ks)*16 + ni)*64 + lane) * 8]) = o;
    }
}

// ---------------------------------------------------------------------------
// Prep B: router weights -> frag-ordered fp16 hi/lo pairs.
//   geom:  ln_g folded in; frag f = ks*2+ni  (ks<8, ni<2), B[n][k]
//   fuse:  frag f = ks*4+ni (ks<2, ni<4)
//   wr:    frag f = ks      (ks<2), cols >=4 zero-padded
//   gb2:   geom_b + ln_b @ geom_w  (beta fold)
// ---------------------------------------------------------------------------
__global__ __launch_bounds__(256) void prep_router_kernel(
    const float* __restrict__ geom_w, const float* __restrict__ geom_b,
    const float* __restrict__ ln_g, const float* __restrict__ ln_b,
    const float* __restrict__ fuse_w, const float* __restrict__ router_w,
    _Float16* __restrict__ wg_hi, _Float16* __restrict__ wg_lo,
    _Float16* __restrict__ wf_hi, _Float16* __restrict__ wf_lo,
    _Float16* __restrict__ wr_hi, _Float16* __restrict__ wr_lo,
    float* __restrict__ gb2)
{
    const int slot = blockIdx.x * 256 + threadIdx.x;
    const int lane = slot & 63;
    const int kg   = lane >> 4;
    const int row  = lane & 15;
    if (slot < 1024) {
        const int f = slot >> 6, ks = f >> 1, ni = f & 1;
        const int n = ni * 16 + row;
        f16x8 hi, lo;
        #pragma unroll
        for (int j = 0; j < 8; ++j) {
            int k = ks * 32 + kg * 8 + j;
            F16Pair p = split16(ln_g[k] * geom_w[k * DG + n]);
            hi[j] = p.hi; lo[j] = p.lo;
        }
        *reinterpret_cast<f16x8*>(&wg_hi[(size_t)slot * 8]) = hi;
        *reinterpret_cast<f16x8*>(&wg_lo[(size_t)slot * 8]) = lo;
    } else if (slot < 1536) {
        const int s = slot - 1024;
        const int f = s >> 6, ks = f >> 2, ni = f & 3;
        const int n = ni * 16 + row;
        f16x8 hi, lo;
        #pragma unroll
        for (int j = 0; j < 8; ++j) {
            int k = ks * 32 + kg * 8 + j;
            F16Pair p = split16(fuse_w[k * FM + n]);
            hi[j] = p.hi; lo[j] = p.lo;
        }
        *reinterpret_cast<f16x8*>(&wf_hi[(size_t)s * 8]) = hi;
        *reinterpret_cast<f16x8*>(&wf_lo[(size_t)s * 8]) = lo;
    } else if (slot < 1664) {
        const int s = slot - 1536;
        const int ks = s >> 6;
        f16x8 hi, lo;
        #pragma unroll
        for (int j = 0; j < 8; ++j) {
            int k = ks * 32 + kg * 8 + j;
            F16Pair p = split16((row < NE) ? router_w[k * NE + row] : 0.f);
            hi[j] = p.hi; lo[j] = p.lo;
        }
        *reinterpret_cast<f16x8*>(&wr_hi[(size_t)s * 8]) = hi;
        *reinterpret_cast<f16x8*>(&wr_lo[(size_t)s * 8]) = lo;
    } else if (slot < 1696) {
        const int n = slot - 1664;   // 0..31
        float acc = geom_b[n];
        for (int k = 0; k < HD; ++k) acc += ln_b[k] * geom_w[k * DG + n];
        gb2[n] = acc;
    }
}

// ---------------------------------------------------------------------------
// Router v2 (MFMA): 256 thr = 4 waves, 64 tokens/block, 16 tokens/wave (M=16).
// Each matmul uses 3-term fp16 split MFMAs (hh+hl+lh) ~= fp32 accuracy.
// Lane (kg=lane>>4, row=lane&15): token = row; A-frags built in registers.
// ---------------------------------------------------------------------------
__global__ __launch_bounds__(256) void router2_kernel(
    const float* __restrict__ h, const float* __restrict__ tok_emb,
    const _Float16* __restrict__ wg_hi, const _Float16* __restrict__ wg_lo,
    const _Float16* __restrict__ wf_hi, const _Float16* __restrict__ wf_lo,
    const _Float16* __restrict__ wr_hi, const _Float16* __restrict__ wr_lo,
    const float* __restrict__ gb2, const float* __restrict__ fuse_b,
    const float* __restrict__ router_b,
    int* __restrict__ top_idx, float* __restrict__ top_prob,
    int* __restrict__ counts, float* __restrict__ importance)
{
    __shared__ __align__(16) _Float16 sg_hi[4][16][40], sg_lo[4][16][40];
    __shared__ __align__(16) _Float16 su_hi[4][16][72], su_lo[4][16][72];
    __shared__ __align__(16) float    s_lg[4][16][4];
    __shared__ float s_imp[NE];
    __shared__ int   s_cnt[NE];

    const int tid  = threadIdx.x;
    const int wv   = tid >> 6;
    const int lane = tid & 63;
    const int kg   = lane >> 4;
    const int row  = lane & 15;
    const int tok  = blockIdx.x * 64 + wv * 16 + row;

    if (tid < NE) { s_imp[tid] = 0.f; s_cnt[tid] = 0; }
    __syncthreads();

    // ---- LN pass 1: sum / sumsq over lane's 64 values (A-frag shaped) ----
    const float* hrow = h + (size_t)tok * HD;
    float s1 = 0.f, s2 = 0.f;
    #pragma unroll
    for (int ks = 0; ks < 8; ++ks) {
        float4 x0 = *reinterpret_cast<const float4*>(hrow + ks * 32 + kg * 8);
        float4 x1 = *reinterpret_cast<const float4*>(hrow + ks * 32 + kg * 8 + 4);
        s1 += (x0.x + x0.y) + (x0.z + x0.w) + (x1.x + x1.y) + (x1.z + x1.w);
        s2 += x0.x*x0.x + x0.y*x0.y + x0.z*x0.z + x0.w*x0.w
            + x1.x*x1.x + x1.y*x1.y + x1.z*x1.z + x1.w*x1.w;
    }
    s1 += __shfl_xor(s1, 16); s1 += __shfl_xor(s1, 32);
    s2 += __shfl_xor(s2, 16); s2 += __shfl_xor(s2, 32);
    const float mu   = s1 * (1.0f / HD);
    const float var  = s2 * (1.0f / HD) - mu * mu;
    const float rstd = rsqrtf(var + 1e-5f);

    // ---- LN pass 2: reload (L2-hot), normalize, fp16 split into A-frags ----
    f16x8 ahi[8], alo[8];
    #pragma unroll
    for (int ks = 0; ks < 8; ++ks) {
        float4 x0 = *reinterpret_cast<const float4*>(hrow + ks * 32 + kg * 8);
        float4 x1 = *reinterpret_cast<const float4*>(hrow + ks * 32 + kg * 8 + 4);
        float v[8] = {x0.x, x0.y, x0.z, x0.w, x1.x, x1.y, x1.z, x1.w};
        #pragma unroll
        for (int j = 0; j < 8; ++j) {
            F16Pair p = split16((v[j] - mu) * rstd);
            ahi[ks][j] = p.hi; alo[ks][j] = p.lo;
        }
    }

    // ---- geom: [16,256]@[256,32], 3-term split MFMA ----
    const f16x8* WGH = reinterpret_cast<const f16x8*>(wg_hi);
    const f16x8* WGL = reinterpret_cast<const f16x8*>(wg_lo);
    f32x4 accg[2];
    #pragma unroll
    for (int ni = 0; ni < 2; ++ni) {
        float bb = gb2[ni * 16 + row];
        accg[ni] = (f32x4){bb, bb, bb, bb};
    }
    #pragma unroll
    for (int ks = 0; ks < 8; ++ks) {
        #pragma unroll
        for (int ni = 0; ni < 2; ++ni) {
            f16x8 bh = WGH[(ks * 2 + ni) * 64 + lane];
            f16x8 bl = WGL[(ks * 2 + ni) * 64 + lane];
            accg[ni] = __builtin_amdgcn_mfma_f32_16x16x32_f16(ahi[ks], bh, accg[ni], 0, 0, 0);
            accg[ni] = __builtin_amdgcn_mfma_f32_16x16x32_f16(alo[ks], bh, accg[ni], 0, 0, 0);
            accg[ni] = __builtin_amdgcn_mfma_f32_16x16x32_f16(ahi[ks], bl, accg[ni], 0, 0, 0);
        }
    }
    // gelu -> split -> LDS transpose tile  (C: token=kg*4+r, col=ni*16+row)
    #pragma unroll
    for (int ni = 0; ni < 2; ++ni)
        #pragma unroll
        for (int r = 0; r < 4; ++r) {
            F16Pair p = split16(gelu_f(accg[ni][r]));
            sg_hi[wv][kg * 4 + r][ni * 16 + row] = p.hi;
            sg_lo[wv][kg * 4 + r][ni * 16 + row] = p.lo;
        }

    // ---- fuse: [16,64]@[64,64]; A = concat(tok_emb, g) ----
    f16x8 a2h[2], a2l[2];
    {
        const float* terow = tok_emb + (size_t)tok * DS;
        float4 x0 = *reinterpret_cast<const float4*>(terow + kg * 8);
        float4 x1 = *reinterpret_cast<const float4*>(terow + kg * 8 + 4);
        float v[8] = {x0.x, x0.y, x0.z, x0.w, x1.x, x1.y, x1.z, x1.w};
        #pragma unroll
        for (int j = 0; j < 8; ++j) {
            F16Pair p = split16(v[j]);
            a2h[0][j] = p.hi; a2l[0][j] = p.lo;
        }
        a2h[1] = *reinterpret_cast<const f16x8*>(&sg_hi[wv][row][kg * 8]);
        a2l[1] = *reinterpret_cast<const f16x8*>(&sg_lo[wv][row][kg * 8]);
    }
    const f16x8* WFH = reinterpret_cast<const f16x8*>(wf_hi);
    const f16x8* WFL = reinterpret_cast<const f16x8*>(wf_lo);
    f32x4 accf[4];
    #pragma unroll
    for (int ni = 0; ni < 4; ++ni) {
        float bb = fuse_b[ni * 16 + row];
        accf[ni] = (f32x4){bb, bb, bb, bb};
    }
    #pragma unroll
    for (int ks = 0; ks < 2; ++ks) {
        #pragma unroll
        for (int ni = 0; ni < 4; ++ni) {
            f16x8 bh = WFH[(ks * 4 + ni) * 64 + lane];
            f16x8 bl = WFL[(ks * 4 + ni) * 64 + lane];
            accf[ni] = __builtin_amdgcn_mfma_f32_16x16x32_f16(a2h[ks], bh, accf[ni], 0, 0, 0);
            accf[ni] = __builtin_amdgcn_mfma_f32_16x16x32_f16(a2l[ks], bh, accf[ni], 0, 0, 0);
            accf[ni] = __builtin_amdgcn_mfma_f32_16x16x32_f16(a2h[ks], bl, accf[ni], 0, 0, 0);
        }
    }
    #pragma unroll
    for (int ni = 0; ni < 4; ++ni)
        #pragma unroll
        for (int r = 0; r < 4; ++r) {
            F16Pair p = split16(gelu_f(accf[ni][r]));
            su_hi[wv][kg * 4 + r][ni * 16 + row] = p.hi;
            su_lo[wv][kg * 4 + r][ni * 16 + row] = p.lo;
        }

    // ---- logits: [16,64]@[64,4] (padded to 16 cols) ----
    const f16x8* WRH = reinterpret_cast<const f16x8*>(wr_hi);
    const f16x8* WRL = reinterpret_cast<const f16x8*>(wr_lo);
    f32x4 accl = (f32x4){0.f, 0.f, 0.f, 0.f};
    #pragma unroll
    for (int ks = 0; ks < 2; ++ks) {
        f16x8 a3h = *reinterpret_cast<const f16x8*>(&su_hi[wv][row][ks * 32 + kg * 8]);
        f16x8 a3l = *reinterpret_cast<const f16x8*>(&su_lo[wv][row][ks * 32 + kg * 8]);
        f16x8 bh = WRH[ks * 64 + lane];
        f16x8 bl = WRL[ks * 64 + lane];
        accl = __builtin_amdgcn_mfma_f32_16x16x32_f16(a3h, bh, accl, 0, 0, 0);
        accl = __builtin_amdgcn_mfma_f32_16x16x32_f16(a3l, bh, accl, 0, 0, 0);
        accl = __builtin_amdgcn_mfma_f32_16x16x32_f16(a3h, bl, accl, 0, 0, 0);
    }
    if (row < NE) {
        float rb = router_b[row];
        #pragma unroll
        for (int r = 0; r < 4; ++r)
            s_lg[wv][kg * 4 + r][row] = accl[r] + rb;
    }
    __syncthreads();

    // ---- softmax/argmax: lanes 0..15, one token each ----
    if (lane < 16) {
        float4 lg = *reinterpret_cast<const float4*>(&s_lg[wv][lane][0]);
        float m  = fmaxf(fmaxf(lg.x, lg.y), fmaxf(lg.z, lg.w));
        float e0 = expf(lg.x - m), e1 = expf(lg.y - m),
              e2 = expf(lg.z - m), e3 = expf(lg.w - m);
        float inv = 1.0f / (e0 + e1 + e2 + e3);
        float p0 = e0 * inv, p1 = e1 * inv, p2 = e2 * inv, p3 = e3 * inv;
        int bi = 0; float bp = p0;
        if (p1 > bp) { bp = p1; bi = 1; }
        if (p2 > bp) { bp = p2; bi = 2; }
        if (p3 > bp) { bp = p3; bi = 3; }
        const int gt = blockIdx.x * 64 + wv * 16 + lane;
        top_idx[gt]  = bi;
        top_prob[gt] = bp;
        atomicAdd(&s_cnt[bi], 1);
        atomicAdd(&s_imp[0], p0); atomicAdd(&s_imp[1], p1);
        atomicAdd(&s_imp[2], p2); atomicAdd(&s_imp[3], p3);
    }
    __syncthreads();
    if (tid < NE) {
        atomicAdd(&importance[tid], s_imp[tid]);
        atomicAdd(&counts[tid], s_cnt[tid]);
    }
}

// ---------------------------------------------------------------------------
__global__ void scan_lb_kernel(const int* __restrict__ counts,
                               const float* __restrict__ importance,
                               int* __restrict__ offsets,
                               float* __restrict__ d_out_lb)
{
    int c0 = counts[0], c1 = counts[1], c2 = counts[2], c3 = counts[3];
    offsets[0] = 0;
    offsets[1] = c0;
    offsets[2] = c0 + c1;
    offsets[3] = c0 + c1 + c2;
    double num = (double)importance[0] * c0 + (double)importance[1] * c1 +
                 (double)importance[2] * c2 + (double)importance[3] * c3;
    double lb = (double)NE * num / ((double)N_TOK * (double)N_TOK + 1e-8);
    *d_out_lb = (float)lb;
}

// ---------------------------------------------------------------------------
__global__ __launch_bounds__(256) void place_kernel(
    const int* __restrict__ top_idx, const int* __restrict__ offsets,
    int* __restrict__ cursors, int* __restrict__ order)
{
    __shared__ int lcnt[NE];
    __shared__ int lbase[NE];
    const int tid = threadIdx.x;
    const int i   = blockIdx.x * 256 + tid;
    if (tid < NE) lcnt[tid] = 0;
    __syncthreads();
    const int e = top_idx[i];
    const int r = atomicAdd(&lcnt[e], 1);
    __syncthreads();
    if (tid < NE) lbase[tid] = (lcnt[tid] > 0) ? atomicAdd(&cursors[tid], lcnt[tid]) : 0;
    __syncthreads();
    order[offsets[e] + lbase[e] + r] = i;
}

// ---------------------------------------------------------------------------
// Expert FFN (unchanged from round 4, verified): 64 tok/block, 8 waves,
// fragment-ordered weights, contiguous 1KB B-loads, conflict-free A ds_reads.
// ---------------------------------------------------------------------------
__global__ __launch_bounds__(512, 2) void expert_mfma_kernel(
    const float* __restrict__ h,
    const unsigned short* __restrict__ w1p,
    const unsigned short* __restrict__ w2p,
    const float* __restrict__ b1, const float* __restrict__ b2,
    const float* __restrict__ top_prob,
    const int* __restrict__ order, const int* __restrict__ counts,
    const int* __restrict__ offsets, float* __restrict__ out)
{
    __shared__ __align__(16) unsigned short sh_h[8 * 4 * 512];
    __shared__ __align__(16) unsigned short sh_a[16 * 4 * 512];
    __shared__ int s_tok[MT];

    const int tid = threadIdx.x;

    int c = blockIdx.x, e;
    for (e = 0; e < NE; ++e) {
        int nch = (counts[e] + MT - 1) / MT;
        if (c < nch) break;
        c -= nch;
    }
    if (e >= NE) return;
    const int cnt  = counts[e];
    const int base = offsets[e] + c * MT;
    const int nt   = min(MT, cnt - c * MT);

    if (tid < MT) s_tok[tid] = (tid < nt) ? order[base + tid] : -1;
    __syncthreads();

    #pragma unroll
    for (int it = 0; it < 4; ++it) {
        int chunk = tid + it * 512;
        int tr = chunk >> 5, q = chunk & 31;
        int t = s_tok[tr];
        float4 v0 = make_float4(0.f,0.f,0.f,0.f), v1 = v0;
        if (t >= 0) {
            const float* p = &h[(size_t)t * HD + q * 8];
            v0 = *reinterpret_cast<const float4*>(p);
            v1 = *reinterpret_cast<const float4*>(p + 4);
        }
        short8 o;
        o[0] = (short)f2bf(v0.x); o[1] = (short)f2bf(v0.y);
        o[2] = (short)f2bf(v0.z); o[3] = (short)f2bf(v0.w);
        o[4] = (short)f2bf(v1.x); o[5] = (short)f2bf(v1.y);
        o[6] = (short)f2bf(v1.z); o[7] = (short)f2bf(v1.w);
        int ks = q >> 2, kg = q & 3, mi = tr >> 4, row = tr & 15;
        *reinterpret_cast<short8*>(&sh_h[((ks*4 + mi)*64 + kg*16 + row) * 8]) = o;
    }
    __syncthreads();

    const int lane  = tid & 63;
    const int wv    = tid >> 6;
    const int row15 = lane & 15;
    const int kg    = lane >> 4;

    const unsigned short* W1 = w1p + (size_t)e * 8 * 32 * 512;
    f32x4 acc1[4][4];
    #pragma unroll
    for (int ni = 0; ni < 4; ++ni) {
        float bb = b1[e * FF + wv * 64 + ni * 16 + row15];
        #pragma unroll
        for (int mi = 0; mi < 4; ++mi) acc1[mi][ni] = (f32x4){bb, bb, bb, bb};
    }
    #pragma unroll
    for (int ks = 0; ks < 8; ++ks) {
        short8 a[4];
        #pragma unroll
        for (int mi = 0; mi < 4; ++mi)
            a[mi] = *reinterpret_cast<const short8*>(&sh_h[((ks*4 + mi)*64 + lane) * 8]);
        #pragma unroll
        for (int ni = 0; ni < 4; ++ni) {
            short8 b = *reinterpret_cast<const short8*>(
                &W1[(size_t)((ks*32 + wv*4 + ni)*64 + lane) * 8]);
            #pragma unroll
            for (int mi = 0; mi < 4; ++mi)
                acc1[mi][ni] = __builtin_amdgcn_mfma_f32_16x16x32_bf16(a[mi], b, acc1[mi][ni], 0, 0, 0);
        }
    }
    #pragma unroll
    for (int ni = 0; ni < 4; ++ni) {
        int ffl = ni * 16 + row15;
        int ks2 = (wv * 64 + ffl) >> 5;
        int kgp = (ffl >> 3) & 3;
        int e8  = ffl & 7;
        #pragma unroll
        for (int mi = 0; mi < 4; ++mi)
            #pragma unroll
            for (int r = 0; r < 4; ++r) {
                int rowp = kg * 4 + r;
                sh_a[((ks2*4 + mi)*64 + kgp*16 + rowp) * 8 + e8] =
                    f2bf(gelu_f(acc1[mi][ni][r]));
            }
    }
    __syncthreads();

    const unsigned short* W2 = w2p + (size_t)e * 16 * 16 * 512;
    f32x4 acc2[4][2];
    #pragma unroll
    for (int ni = 0; ni < 2; ++ni) {
        float bb = b2[e * HD + wv * 32 + ni * 16 + row15];
        #pragma unroll
        for (int mi = 0; mi < 4; ++mi) acc2[mi][ni] = (f32x4){bb, bb, bb, bb};
    }
    #pragma unroll
    for (int ks = 0; ks < 16; ++ks) {
        short8 a2[4];
        #pragma unroll
        for (int mi = 0; mi < 4; ++mi)
            a2[mi] = *reinterpret_cast<const short8*>(&sh_a[((ks*4 + mi)*64 + lane) * 8]);
        #pragma unroll
        for (int ni = 0; ni < 2; ++ni) {
            short8 b = *reinterpret_cast<const short8*>(
                &W2[(size_t)((ks*16 + wv*2 + ni)*64 + lane) * 8]);
            #pragma unroll
            for (int mi = 0; mi < 4; ++mi)
                acc2[mi][ni] = __builtin_amdgcn_mfma_f32_16x16x32_bf16(a2[mi], b, acc2[mi][ni], 0, 0, 0);
        }
    }

    #pragma unroll
    for (int mi = 0; mi < 4; ++mi)
        #pragma unroll
        for (int r = 0; r < 4; ++r) {
            int gt = s_tok[mi * 16 + kg * 4 + r];
            if (gt < 0) continue;
            float tp = 0.5f * top_prob[gt];
            #pragma unroll
            for (int ni = 0; ni < 2; ++ni) {
                int cl = wv * 32 + ni * 16 + row15;
                float res = h[(size_t)gt * HD + cl];
                out[(size_t)gt * HD + cl] = res + tp * acc2[mi][ni][r];
            }
        }
}

// ---------------------------------------------------------------------------
extern "C" void kernel_launch(void* const* d_in, const int* in_sizes, int n_in,
                              void* d_out, int out_size, void* d_ws, size_t ws_size,
                              hipStream_t stream)
{
    const float* h        = (const float*)d_in[0];
    const float* tok_emb  = (const float*)d_in[1];
    /* d_in[2] = is_mask: all zeros, unused by the reference math */
    const float* ln_g     = (const float*)d_in[3];
    const float* ln_b     = (const float*)d_in[4];
    const float* geom_w   = (const float*)d_in[5];
    const float* geom_b   = (const float*)d_in[6];
    const float* fuse_w   = (const float*)d_in[7];
    const float* fuse_b   = (const float*)d_in[8];
    const float* router_w = (const float*)d_in[9];
    const float* router_b = (const float*)d_in[10];
    const float* w1       = (const float*)d_in[11];
    const float* b1       = (const float*)d_in[12];
    const float* w2       = (const float*)d_in[13];
    const float* b2       = (const float*)d_in[14];
    float* out = (float*)d_out;

    // workspace layout (4B word units from d_ws)
    int*   counts     = (int*)d_ws;                   // [4]
    float* importance = (float*)d_ws + 4;             // [4]
    int*   offsets    = (int*)d_ws + 8;               // [4]
    int*   cursors    = (int*)d_ws + 12;              // [4]
    int*   top_idx    = (int*)d_ws + 64;              // [N]
    float* top_prob   = (float*)d_ws + 64 + N_TOK;    // [N]
    int*   order      = (int*)d_ws + 64 + 2 * N_TOK;  // [N]
    unsigned short* w1p = (unsigned short*)((int*)d_ws + 64 + 3 * N_TOK); // 1MB
    unsigned short* w2p = w1p + (size_t)NE * FF * HD;                     // 1MB
    _Float16* wg_hi = (_Float16*)(w2p + (size_t)NE * FF * HD);
    _Float16* wg_lo = wg_hi + 8192;
    _Float16* wf_hi = wg_lo + 8192;
    _Float16* wf_lo = wf_hi + 4096;
    _Float16* wr_hi = wf_lo + 4096;
    _Float16* wr_lo = wr_hi + 1024;
    float*    gb2   = (float*)(wr_lo + 1024);         // [32]

    hipMemsetAsync(d_ws, 0, 64 * sizeof(int), stream);

    prep_weights_kernel<<<512, 256, 0, stream>>>(w1, w2, w1p, w2p);
    prep_router_kernel<<<7, 256, 0, stream>>>(
        geom_w, geom_b, ln_g, ln_b, fuse_w, router_w,
        wg_hi, wg_lo, wf_hi, wf_lo, wr_hi, wr_lo, gb2);

    router2_kernel<<<N_TOK / 64, 256, 0, stream>>>(
        h, tok_emb, wg_hi, wg_lo, wf_hi, wf_lo, wr_hi, wr_lo,
        gb2, fuse_b, router_b, top_idx, top_prob, counts, importance);

    scan_lb_kernel<<<1, 1, 0, stream>>>(counts, importance, offsets,
                                        &out[(size_t)N_TOK * HD]);

    place_kernel<<<N_TOK / 256, 256, 0, stream>>>(top_idx, offsets, cursors, order);

    expert_mfma_kernel<<<N_TOK / MT + NE, 512, 0, stream>>>(
        h, w1p, w2p, b1, b2, top_prob, order, counts, offsets, out);
}

// Round 7
// 256.862 us; speedup vs baseline: 7.5568x; 1.2287x over previous
//
#include <hip/hip_runtime.h>
#include <hip/hip_bf16.h>
#include <math.h>

#define N_TOK 131072
#define HD    256
#define DS    32
#define DG    32
#define FM    64
#define NE    4
#define FF    512
#define MT    64   // tokens per expert block (8 waves, 512 threads)

typedef short    short8 __attribute__((ext_vector_type(8)));
typedef _Float16 f16x8  __attribute__((ext_vector_type(8)));
typedef float    f32x4  __attribute__((ext_vector_type(4)));

struct F16Pair { _Float16 hi, lo; };

__device__ __forceinline__ float gelu_f(float x) {
    return 0.5f * x * (1.0f + erff(x * 0.70710678118654752f));
}
__device__ __forceinline__ unsigned short f2bf(float x) {
    union { __hip_bfloat16 b; unsigned short u; } cv;
    cv.b = __float2bfloat16(x);
    return cv.u;
}
__device__ __forceinline__ F16Pair split16(float v) {
    F16Pair p;
    p.hi = (_Float16)v;
    p.lo = (_Float16)(v - (float)p.hi);
    return p;
}

// ---------------------------------------------------------------------------
// Prep A: expert weights -> MFMA-fragment-ordered bf16 (unchanged, verified).
// Lane (kg=lane>>4,row=lane&15) of frag (ks,ni) holds W[k=ks*32+kg*8+j][n=ni*16+row]
// = A-fragment with M = n (output col), used as the A operand after the swap.
// ---------------------------------------------------------------------------
__global__ __launch_bounds__(256) void prep_weights_kernel(
    const float* __restrict__ w1, const float* __restrict__ w2,
    unsigned short* __restrict__ w1p, unsigned short* __restrict__ w2p)
{
    int t = (blockIdx.x & 255) * 256 + threadIdx.x;
    const int lane = t & 63;
    const int kg   = lane >> 4;
    const int row  = lane & 15;
    if (blockIdx.x < 256) {
        const int ni = (t >> 6) & 31;
        const int ks = (t >> 11) & 7;
        const int e  = t >> 14;
        const int n  = ni * 16 + row;
        const int k0 = ks * 32 + kg * 8;
        short8 o;
        #pragma unroll
        for (int j = 0; j < 8; ++j)
            o[j] = (short)f2bf(w1[((size_t)e * HD + k0 + j) * FF + n]);
        *reinterpret_cast<short8*>(&w1p[(size_t)(((e*8 + ks)*32 + ni)*64 + lane) * 8]) = o;
    } else {
        const int ni = (t >> 6) & 15;
        const int ks = (t >> 10) & 15;
        const int e  = t >> 14;
        const int n  = ni * 16 + row;
        const int k0 = ks * 32 + kg * 8;
        short8 o;
        #pragma unroll
        for (int j = 0; j < 8; ++j)
            o[j] = (short)f2bf(w2[((size_t)e * FF + k0 + j) * HD + n]);
        *reinterpret_cast<short8*>(&w2p[(size_t)(((e*16 + ks)*16 + ni)*64 + lane) * 8]) = o;
    }
}

// ---------------------------------------------------------------------------
// Prep B: router weights -> frag-ordered fp16 hi/lo pairs (unchanged).
// ---------------------------------------------------------------------------
__global__ __launch_bounds__(256) void prep_router_kernel(
    const float* __restrict__ geom_w, const float* __restrict__ geom_b,
    const float* __restrict__ ln_g, const float* __restrict__ ln_b,
    const float* __restrict__ fuse_w, const float* __restrict__ router_w,
    _Float16* __restrict__ wg_hi, _Float16* __restrict__ wg_lo,
    _Float16* __restrict__ wf_hi, _Float16* __restrict__ wf_lo,
    _Float16* __restrict__ wr_hi, _Float16* __restrict__ wr_lo,
    float* __restrict__ gb2)
{
    const int slot = blockIdx.x * 256 + threadIdx.x;
    const int lane = slot & 63;
    const int kg   = lane >> 4;
    const int row  = lane & 15;
    if (slot < 1024) {
        const int f = slot >> 6, ks = f >> 1, ni = f & 1;
        const int n = ni * 16 + row;
        f16x8 hi, lo;
        #pragma unroll
        for (int j = 0; j < 8; ++j) {
            int k = ks * 32 + kg * 8 + j;
            F16Pair p = split16(ln_g[k] * geom_w[k * DG + n]);
            hi[j] = p.hi; lo[j] = p.lo;
        }
        *reinterpret_cast<f16x8*>(&wg_hi[(size_t)slot * 8]) = hi;
        *reinterpret_cast<f16x8*>(&wg_lo[(size_t)slot * 8]) = lo;
    } else if (slot < 1536) {
        const int s = slot - 1024;
        const int f = s >> 6, ks = f >> 2, ni = f & 3;
        const int n = ni * 16 + row;
        f16x8 hi, lo;
        #pragma unroll
        for (int j = 0; j < 8; ++j) {
            int k = ks * 32 + kg * 8 + j;
            F16Pair p = split16(fuse_w[k * FM + n]);
            hi[j] = p.hi; lo[j] = p.lo;
        }
        *reinterpret_cast<f16x8*>(&wf_hi[(size_t)s * 8]) = hi;
        *reinterpret_cast<f16x8*>(&wf_lo[(size_t)s * 8]) = lo;
    } else if (slot < 1664) {
        const int s = slot - 1536;
        const int ks = s >> 6;
        f16x8 hi, lo;
        #pragma unroll
        for (int j = 0; j < 8; ++j) {
            int k = ks * 32 + kg * 8 + j;
            F16Pair p = split16((row < NE) ? router_w[k * NE + row] : 0.f);
            hi[j] = p.hi; lo[j] = p.lo;
        }
        *reinterpret_cast<f16x8*>(&wr_hi[(size_t)s * 8]) = hi;
        *reinterpret_cast<f16x8*>(&wr_lo[(size_t)s * 8]) = lo;
    } else if (slot < 1696) {
        const int n = slot - 1664;   // 0..31
        float acc = geom_b[n];
        for (int k = 0; k < HD; ++k) acc += ln_b[k] * geom_w[k * DG + n];
        gb2[n] = acc;
    }
}

// ---------------------------------------------------------------------------
// Router v2 (MFMA, unchanged from round 6 — verified).
// ---------------------------------------------------------------------------
__global__ __launch_bounds__(256) void router2_kernel(
    const float* __restrict__ h, const float* __restrict__ tok_emb,
    const _Float16* __restrict__ wg_hi, const _Float16* __restrict__ wg_lo,
    const _Float16* __restrict__ wf_hi, const _Float16* __restrict__ wf_lo,
    const _Float16* __restrict__ wr_hi, const _Float16* __restrict__ wr_lo,
    const float* __restrict__ gb2, const float* __restrict__ fuse_b,
    const float* __restrict__ router_b,
    int* __restrict__ top_idx, float* __restrict__ top_prob,
    int* __restrict__ counts, float* __restrict__ importance)
{
    __shared__ __align__(16) _Float16 sg_hi[4][16][40], sg_lo[4][16][40];
    __shared__ __align__(16) _Float16 su_hi[4][16][72], su_lo[4][16][72];
    __shared__ __align__(16) float    s_lg[4][16][4];
    __shared__ float s_imp[NE];
    __shared__ int   s_cnt[NE];

    const int tid  = threadIdx.x;
    const int wv   = tid >> 6;
    const int lane = tid & 63;
    const int kg   = lane >> 4;
    const int row  = lane & 15;
    const int tok  = blockIdx.x * 64 + wv * 16 + row;

    if (tid < NE) { s_imp[tid] = 0.f; s_cnt[tid] = 0; }
    __syncthreads();

    const float* hrow = h + (size_t)tok * HD;
    float s1 = 0.f, s2 = 0.f;
    #pragma unroll
    for (int ks = 0; ks < 8; ++ks) {
        float4 x0 = *reinterpret_cast<const float4*>(hrow + ks * 32 + kg * 8);
        float4 x1 = *reinterpret_cast<const float4*>(hrow + ks * 32 + kg * 8 + 4);
        s1 += (x0.x + x0.y) + (x0.z + x0.w) + (x1.x + x1.y) + (x1.z + x1.w);
        s2 += x0.x*x0.x + x0.y*x0.y + x0.z*x0.z + x0.w*x0.w
            + x1.x*x1.x + x1.y*x1.y + x1.z*x1.z + x1.w*x1.w;
    }
    s1 += __shfl_xor(s1, 16); s1 += __shfl_xor(s1, 32);
    s2 += __shfl_xor(s2, 16); s2 += __shfl_xor(s2, 32);
    const float mu   = s1 * (1.0f / HD);
    const float var  = s2 * (1.0f / HD) - mu * mu;
    const float rstd = rsqrtf(var + 1e-5f);

    f16x8 ahi[8], alo[8];
    #pragma unroll
    for (int ks = 0; ks < 8; ++ks) {
        float4 x0 = *reinterpret_cast<const float4*>(hrow + ks * 32 + kg * 8);
        float4 x1 = *reinterpret_cast<const float4*>(hrow + ks * 32 + kg * 8 + 4);
        float v[8] = {x0.x, x0.y, x0.z, x0.w, x1.x, x1.y, x1.z, x1.w};
        #pragma unroll
        for (int j = 0; j < 8; ++j) {
            F16Pair p = split16((v[j] - mu) * rstd);
            ahi[ks][j] = p.hi; alo[ks][j] = p.lo;
        }
    }

    const f16x8* WGH = reinterpret_cast<const f16x8*>(wg_hi);
    const f16x8* WGL = reinterpret_cast<const f16x8*>(wg_lo);
    f32x4 accg[2];
    #pragma unroll
    for (int ni = 0; ni < 2; ++ni) {
        float bb = gb2[ni * 16 + row];
        accg[ni] = (f32x4){bb, bb, bb, bb};
    }
    #pragma unroll
    for (int ks = 0; ks < 8; ++ks) {
        #pragma unroll
        for (int ni = 0; ni < 2; ++ni) {
            f16x8 bh = WGH[(ks * 2 + ni) * 64 + lane];
            f16x8 bl = WGL[(ks * 2 + ni) * 64 + lane];
            accg[ni] = __builtin_amdgcn_mfma_f32_16x16x32_f16(ahi[ks], bh, accg[ni], 0, 0, 0);
            accg[ni] = __builtin_amdgcn_mfma_f32_16x16x32_f16(alo[ks], bh, accg[ni], 0, 0, 0);
            accg[ni] = __builtin_amdgcn_mfma_f32_16x16x32_f16(ahi[ks], bl, accg[ni], 0, 0, 0);
        }
    }
    #pragma unroll
    for (int ni = 0; ni < 2; ++ni)
        #pragma unroll
        for (int r = 0; r < 4; ++r) {
            F16Pair p = split16(gelu_f(accg[ni][r]));
            sg_hi[wv][kg * 4 + r][ni * 16 + row] = p.hi;
            sg_lo[wv][kg * 4 + r][ni * 16 + row] = p.lo;
        }

    f16x8 a2h[2], a2l[2];
    {
        const float* terow = tok_emb + (size_t)tok * DS;
        float4 x0 = *reinterpret_cast<const float4*>(terow + kg * 8);
        float4 x1 = *reinterpret_cast<const float4*>(terow + kg * 8 + 4);
        float v[8] = {x0.x, x0.y, x0.z, x0.w, x1.x, x1.y, x1.z, x1.w};
        #pragma unroll
        for (int j = 0; j < 8; ++j) {
            F16Pair p = split16(v[j]);
            a2h[0][j] = p.hi; a2l[0][j] = p.lo;
        }
        a2h[1] = *reinterpret_cast<const f16x8*>(&sg_hi[wv][row][kg * 8]);
        a2l[1] = *reinterpret_cast<const f16x8*>(&sg_lo[wv][row][kg * 8]);
    }
    const f16x8* WFH = reinterpret_cast<const f16x8*>(wf_hi);
    const f16x8* WFL = reinterpret_cast<const f16x8*>(wf_lo);
    f32x4 accf[4];
    #pragma unroll
    for (int ni = 0; ni < 4; ++ni) {
        float bb = fuse_b[ni * 16 + row];
        accf[ni] = (f32x4){bb, bb, bb, bb};
    }
    #pragma unroll
    for (int ks = 0; ks < 2; ++ks) {
        #pragma unroll
        for (int ni = 0; ni < 4; ++ni) {
            f16x8 bh = WFH[(ks * 4 + ni) * 64 + lane];
            f16x8 bl = WFL[(ks * 4 + ni) * 64 + lane];
            accf[ni] = __builtin_amdgcn_mfma_f32_16x16x32_f16(a2h[ks], bh, accf[ni], 0, 0, 0);
            accf[ni] = __builtin_amdgcn_mfma_f32_16x16x32_f16(a2l[ks], bh, accf[ni], 0, 0, 0);
            accf[ni] = __builtin_amdgcn_mfma_f32_16x16x32_f16(a2h[ks], bl, accf[ni], 0, 0, 0);
        }
    }
    #pragma unroll
    for (int ni = 0; ni < 4; ++ni)
        #pragma unroll
        for (int r = 0; r < 4; ++r) {
            F16Pair p = split16(gelu_f(accf[ni][r]));
            su_hi[wv][kg * 4 + r][ni * 16 + row] = p.hi;
            su_lo[wv][kg * 4 + r][ni * 16 + row] = p.lo;
        }

    const f16x8* WRH = reinterpret_cast<const f16x8*>(wr_hi);
    const f16x8* WRL = reinterpret_cast<const f16x8*>(wr_lo);
    f32x4 accl = (f32x4){0.f, 0.f, 0.f, 0.f};
    #pragma unroll
    for (int ks = 0; ks < 2; ++ks) {
        f16x8 a3h = *reinterpret_cast<const f16x8*>(&su_hi[wv][row][ks * 32 + kg * 8]);
        f16x8 a3l = *reinterpret_cast<const f16x8*>(&su_lo[wv][row][ks * 32 + kg * 8]);
        f16x8 bh = WRH[ks * 64 + lane];
        f16x8 bl = WRL[ks * 64 + lane];
        accl = __builtin_amdgcn_mfma_f32_16x16x32_f16(a3h, bh, accl, 0, 0, 0);
        accl = __builtin_amdgcn_mfma_f32_16x16x32_f16(a3l, bh, accl, 0, 0, 0);
        accl = __builtin_amdgcn_mfma_f32_16x16x32_f16(a3h, bl, accl, 0, 0, 0);
    }
    if (row < NE) {
        float rb = router_b[row];
        #pragma unroll
        for (int r = 0; r < 4; ++r)
            s_lg[wv][kg * 4 + r][row] = accl[r] + rb;
    }
    __syncthreads();

    if (lane < 16) {
        float4 lg = *reinterpret_cast<const float4*>(&s_lg[wv][lane][0]);
        float m  = fmaxf(fmaxf(lg.x, lg.y), fmaxf(lg.z, lg.w));
        float e0 = expf(lg.x - m), e1 = expf(lg.y - m),
              e2 = expf(lg.z - m), e3 = expf(lg.w - m);
        float inv = 1.0f / (e0 + e1 + e2 + e3);
        float p0 = e0 * inv, p1 = e1 * inv, p2 = e2 * inv, p3 = e3 * inv;
        int bi = 0; float bp = p0;
        if (p1 > bp) { bp = p1; bi = 1; }
        if (p2 > bp) { bp = p2; bi = 2; }
        if (p3 > bp) { bp = p3; bi = 3; }
        const int gt = blockIdx.x * 64 + wv * 16 + lane;
        top_idx[gt]  = bi;
        top_prob[gt] = bp;
        atomicAdd(&s_cnt[bi], 1);
        atomicAdd(&s_imp[0], p0); atomicAdd(&s_imp[1], p1);
        atomicAdd(&s_imp[2], p2); atomicAdd(&s_imp[3], p3);
    }
    __syncthreads();
    if (tid < NE) {
        atomicAdd(&importance[tid], s_imp[tid]);
        atomicAdd(&counts[tid], s_cnt[tid]);
    }
}

// ---------------------------------------------------------------------------
__global__ void scan_lb_kernel(const int* __restrict__ counts,
                               const float* __restrict__ importance,
                               int* __restrict__ offsets,
                               float* __restrict__ d_out_lb)
{
    int c0 = counts[0], c1 = counts[1], c2 = counts[2], c3 = counts[3];
    offsets[0] = 0;
    offsets[1] = c0;
    offsets[2] = c0 + c1;
    offsets[3] = c0 + c1 + c2;
    double num = (double)importance[0] * c0 + (double)importance[1] * c1 +
                 (double)importance[2] * c2 + (double)importance[3] * c3;
    double lb = (double)NE * num / ((double)N_TOK * (double)N_TOK + 1e-8);
    *d_out_lb = (float)lb;
}

// ---------------------------------------------------------------------------
__global__ __launch_bounds__(256) void place_kernel(
    const int* __restrict__ top_idx, const int* __restrict__ offsets,
    int* __restrict__ cursors, int* __restrict__ order)
{
    __shared__ int lcnt[NE];
    __shared__ int lbase[NE];
    const int tid = threadIdx.x;
    const int i   = blockIdx.x * 256 + tid;
    if (tid < NE) lcnt[tid] = 0;
    __syncthreads();
    const int e = top_idx[i];
    const int r = atomicAdd(&lcnt[e], 1);
    __syncthreads();
    if (tid < NE) lbase[tid] = (lcnt[tid] > 0) ? atomicAdd(&cursors[tid], lcnt[tid]) : 0;
    __syncthreads();
    order[offsets[e] + lbase[e] + r] = i;
}

// ---------------------------------------------------------------------------
// Expert FFN v3: operand-swapped MFMA (A=weights rows=n, B=tokens cols) +
// two-pass FF split. LDS 64.3 KB -> 2 blocks/CU (4 waves/SIMD).
//   pass p: L1 over FF-half [p*256,p*256+256) (wave owns 32 cols) ->
//           packed ushort4 act writes -> barrier -> L2 partial accumulate.
// Epilogue: float4 residual + float4 store (4 consecutive n per acc reg).
// ---------------------------------------------------------------------------
__global__ __launch_bounds__(512, 4) void expert_mfma_kernel(
    const float* __restrict__ h,
    const unsigned short* __restrict__ w1p,
    const unsigned short* __restrict__ w2p,
    const float* __restrict__ b1, const float* __restrict__ b2,
    const float* __restrict__ top_prob,
    const int* __restrict__ order, const int* __restrict__ counts,
    const int* __restrict__ offsets, float* __restrict__ out)
{
    __shared__ __align__(16) unsigned short sh_h[8 * 4 * 512];   // 32 KB frag-ordered h
    __shared__ __align__(16) unsigned short sh_a[8 * 4 * 512];   // 32 KB per-pass act
    __shared__ int s_tok[MT];

    const int tid = threadIdx.x;

    int c = blockIdx.x, e;
    for (e = 0; e < NE; ++e) {
        int nch = (counts[e] + MT - 1) / MT;
        if (c < nch) break;
        c -= nch;
    }
    if (e >= NE) return;
    const int cnt  = counts[e];
    const int base = offsets[e] + c * MT;
    const int nt   = min(MT, cnt - c * MT);

    if (tid < MT) s_tok[tid] = (tid < nt) ? order[base + tid] : -1;
    __syncthreads();

    // gather h rows -> frag-ordered bf16 LDS (B-fragments: lane holds token=row)
    #pragma unroll
    for (int it = 0; it < 4; ++it) {
        int chunk = tid + it * 512;
        int tr = chunk >> 5, q = chunk & 31;
        int t = s_tok[tr];
        float4 v0 = make_float4(0.f,0.f,0.f,0.f), v1 = v0;
        if (t >= 0) {
            const float* p = &h[(size_t)t * HD + q * 8];
            v0 = *reinterpret_cast<const float4*>(p);
            v1 = *reinterpret_cast<const float4*>(p + 4);
        }
        short8 o;
        o[0] = (short)f2bf(v0.x); o[1] = (short)f2bf(v0.y);
        o[2] = (short)f2bf(v0.z); o[3] = (short)f2bf(v0.w);
        o[4] = (short)f2bf(v1.x); o[5] = (short)f2bf(v1.y);
        o[6] = (short)f2bf(v1.z); o[7] = (short)f2bf(v1.w);
        int ks = q >> 2, kg = q & 3, mi = tr >> 4, row = tr & 15;
        *reinterpret_cast<short8*>(&sh_h[((ks*4 + mi)*64 + kg*16 + row) * 8]) = o;
    }
    __syncthreads();

    const int lane  = tid & 63;
    const int wv    = tid >> 6;       // 0..7
    const int row15 = lane & 15;
    const int kg    = lane >> 4;

    const unsigned short* W1 = w1p + (size_t)e * 8 * 32 * 512;
    const unsigned short* W2 = w2p + (size_t)e * 16 * 16 * 512;

    // L2 accumulators: wave owns HD cols [wv*32, wv*32+32); acc2[ni][mi]
    // holds out[token=mi*16+row15][n = wv*32+ni*16+kg*4+r] (n on C-rows).
    f32x4 acc2[2][4];
    #pragma unroll
    for (int ni = 0; ni < 2; ++ni) {
        f32x4 bb = *reinterpret_cast<const f32x4*>(&b2[e * HD + wv * 32 + ni * 16 + kg * 4]);
        #pragma unroll
        for (int mi = 0; mi < 4; ++mi) acc2[ni][mi] = bb;
    }

    #pragma unroll
    for (int p = 0; p < 2; ++p) {
        // -------- L1 over FF-half p: wave owns cols p*256+wv*32 .. +32 -----
        f32x4 acc1[2][4];
        #pragma unroll
        for (int ni = 0; ni < 2; ++ni) {
            f32x4 bb = *reinterpret_cast<const f32x4*>(
                &b1[e * FF + p * 256 + wv * 32 + ni * 16 + kg * 4]);
            #pragma unroll
            for (int mi = 0; mi < 4; ++mi) acc1[ni][mi] = bb;
        }
        #pragma unroll
        for (int ks = 0; ks < 8; ++ks) {
            short8 bh[4];
            #pragma unroll
            for (int mi = 0; mi < 4; ++mi)
                bh[mi] = *reinterpret_cast<const short8*>(&sh_h[((ks*4 + mi)*64 + lane) * 8]);
            #pragma unroll
            for (int ni = 0; ni < 2; ++ni) {
                short8 aw = *reinterpret_cast<const short8*>(
                    &W1[(size_t)((ks*32 + p*16 + wv*2 + ni)*64 + lane) * 8]);
                #pragma unroll
                for (int mi = 0; mi < 4; ++mi)
                    acc1[ni][mi] = __builtin_amdgcn_mfma_f32_16x16x32_bf16(aw, bh[mi], acc1[ni][mi], 0, 0, 0);
            }
        }
        if (p == 1) __syncthreads();   // all pass-0 L2 reads of sh_a done

        // -------- gelu + packed act write (4 consecutive n per acc) --------
        // n_local = wv*32 + ni*16 + kg*4 + r  ->  ksl=wv, kgp=ni*2+(kg>>1),
        // e8 base=(kg&1)*4; token row = row15 of tile mi.
        #pragma unroll
        for (int ni = 0; ni < 2; ++ni) {
            const int kgp = ni * 2 + (kg >> 1);
            #pragma unroll
            for (int mi = 0; mi < 4; ++mi) {
                ushort4 pk;
                pk.x = f2bf(gelu_f(acc1[ni][mi][0]));
                pk.y = f2bf(gelu_f(acc1[ni][mi][1]));
                pk.z = f2bf(gelu_f(acc1[ni][mi][2]));
                pk.w = f2bf(gelu_f(acc1[ni][mi][3]));
                *reinterpret_cast<ushort4*>(
                    &sh_a[(((wv*4 + mi)*64 + kgp*16 + row15) * 8 + (kg & 1) * 4)]) = pk;
            }
        }
        __syncthreads();

        // -------- L2 partial over this FF-half ----------------------------
        #pragma unroll
        for (int l = 0; l < 8; ++l) {
            short8 ba[4];
            #pragma unroll
            for (int mi = 0; mi < 4; ++mi)
                ba[mi] = *reinterpret_cast<const short8*>(&sh_a[((l*4 + mi)*64 + lane) * 8]);
            #pragma unroll
            for (int ni = 0; ni < 2; ++ni) {
                short8 aw = *reinterpret_cast<const short8*>(
                    &W2[(size_t)(((p*8 + l)*16 + wv*2 + ni)*64 + lane) * 8]);
                #pragma unroll
                for (int mi = 0; mi < 4; ++mi)
                    acc2[ni][mi] = __builtin_amdgcn_mfma_f32_16x16x32_bf16(aw, ba[mi], acc2[ni][mi], 0, 0, 0);
            }
        }
    }

    // -------- epilogue: float4 residual + store (4 consecutive n) ---------
    #pragma unroll
    for (int mi = 0; mi < 4; ++mi) {
        int gt = s_tok[mi * 16 + row15];
        if (gt < 0) continue;
        float tp = 0.5f * top_prob[gt];
        #pragma unroll
        for (int ni = 0; ni < 2; ++ni) {
            int nb = wv * 32 + ni * 16 + kg * 4;
            float4 res = *reinterpret_cast<const float4*>(&h[(size_t)gt * HD + nb]);
            float4 o;
            o.x = res.x + tp * acc2[ni][mi][0];
            o.y = res.y + tp * acc2[ni][mi][1];
            o.z = res.z + tp * acc2[ni][mi][2];
            o.w = res.w + tp * acc2[ni][mi][3];
            *reinterpret_cast<float4*>(&out[(size_t)gt * HD + nb]) = o;
        }
    }
}

// ---------------------------------------------------------------------------
extern "C" void kernel_launch(void* const* d_in, const int* in_sizes, int n_in,
                              void* d_out, int out_size, void* d_ws, size_t ws_size,
                              hipStream_t stream)
{
    const float* h        = (const float*)d_in[0];
    const float* tok_emb  = (const float*)d_in[1];
    /* d_in[2] = is_mask: all zeros, unused by the reference math */
    const float* ln_g     = (const float*)d_in[3];
    const float* ln_b     = (const float*)d_in[4];
    const float* geom_w   = (const float*)d_in[5];
    const float* geom_b   = (const float*)d_in[6];
    const float* fuse_w   = (const float*)d_in[7];
    const float* fuse_b   = (const float*)d_in[8];
    const float* router_w = (const float*)d_in[9];
    const float* router_b = (const float*)d_in[10];
    const float* w1       = (const float*)d_in[11];
    const float* b1       = (const float*)d_in[12];
    const float* w2       = (const float*)d_in[13];
    const float* b2       = (const float*)d_in[14];
    float* out = (float*)d_out;

    // workspace layout (4B word units from d_ws)
    int*   counts     = (int*)d_ws;                   // [4]
    float* importance = (float*)d_ws + 4;             // [4]
    int*   offsets    = (int*)d_ws + 8;               // [4]
    int*   cursors    = (int*)d_ws + 12;              // [4]
    int*   top_idx    = (int*)d_ws + 64;              // [N]
    float* top_prob   = (float*)d_ws + 64 + N_TOK;    // [N]
    int*   order      = (int*)d_ws + 64 + 2 * N_TOK;  // [N]
    unsigned short* w1p = (unsigned short*)((int*)d_ws + 64 + 3 * N_TOK); // 1MB
    unsigned short* w2p = w1p + (size_t)NE * FF * HD;                     // 1MB
    _Float16* wg_hi = (_Float16*)(w2p + (size_t)NE * FF * HD);
    _Float16* wg_lo = wg_hi + 8192;
    _Float16* wf_hi = wg_lo + 8192;
    _Float16* wf_lo = wf_hi + 4096;
    _Float16* wr_hi = wf_lo + 4096;
    _Float16* wr_lo = wr_hi + 1024;
    float*    gb2   = (float*)(wr_lo + 1024);         // [32]

    hipMemsetAsync(d_ws, 0, 64 * sizeof(int), stream);

    prep_weights_kernel<<<512, 256, 0, stream>>>(w1, w2, w1p, w2p);
    prep_router_kernel<<<7, 256, 0, stream>>>(
        geom_w, geom_b, ln_g, ln_b, fuse_w, router_w,
        wg_hi, wg_lo, wf_hi, wf_lo, wr_hi, wr_lo, gb2);

    router2_kernel<<<N_TOK / 64, 256, 0, stream>>>(
        h, tok_emb, wg_hi, wg_lo, wf_hi, wf_lo, wr_hi, wr_lo,
        gb2, fuse_b, router_b, top_idx, top_prob, counts, importance);

    scan_lb_kernel<<<1, 1, 0, stream>>>(counts, importance, offsets,
                                        &out[(size_t)N_TOK * HD]);

    place_kernel<<<N_TOK / 256, 256, 0, stream>>>(top_idx, offsets, cursors, order);

    expert_mfma_kernel<<<N_TOK / MT + NE, 512, 0, stream>>>(
        h, w1p, w2p, b1, b2, top_prob, order, counts, offsets, out);
}

// Round 8
// 250.175 us; speedup vs baseline: 7.7588x; 1.0267x over previous
//
#include <hip/hip_runtime.h>
#include <hip/hip_bf16.h>
#include <math.h>

#define N_TOK 131072
#define HD    256
#define DS    32
#define DG    32
#define FM    64
#define NE    4
#define FF    512
#define MT    64   // tokens per expert block (8 waves, 512 threads)

typedef short    short8 __attribute__((ext_vector_type(8)));
typedef _Float16 f16x8  __attribute__((ext_vector_type(8)));
typedef float    f32x4  __attribute__((ext_vector_type(4)));

struct F16Pair { _Float16 hi, lo; };

__device__ __forceinline__ float gelu_f(float x) {        // exact erf (router)
    return 0.5f * x * (1.0f + erff(x * 0.70710678118654752f));
}
__device__ __forceinline__ float gelu_t(float x) {        // tanh-form (expert)
    return x / (1.0f + __expf(-1.5957691216057308f * (x + 0.044715f * x * x * x)));
}
__device__ __forceinline__ unsigned short f2bf(float x) {
    union { __hip_bfloat16 b; unsigned short u; } cv;
    cv.b = __float2bfloat16(x);
    return cv.u;
}
__device__ __forceinline__ F16Pair split16(float v) {
    F16Pair p;
    p.hi = (_Float16)v;
    p.lo = (_Float16)(v - (float)p.hi);
    return p;
}

// ---------------------------------------------------------------------------
// Prep (fused): blocks 0..511 repack expert weights (frag-ordered bf16);
// blocks 512..518 build router fp16 hi/lo tables + folded gb2.
// ---------------------------------------------------------------------------
__global__ __launch_bounds__(256) void prep_all_kernel(
    const float* __restrict__ w1, const float* __restrict__ w2,
    unsigned short* __restrict__ w1p, unsigned short* __restrict__ w2p,
    const float* __restrict__ geom_w, const float* __restrict__ geom_b,
    const float* __restrict__ ln_g, const float* __restrict__ ln_b,
    const float* __restrict__ fuse_w, const float* __restrict__ router_w,
    _Float16* __restrict__ wg_hi, _Float16* __restrict__ wg_lo,
    _Float16* __restrict__ wf_hi, _Float16* __restrict__ wf_lo,
    _Float16* __restrict__ wr_hi, _Float16* __restrict__ wr_lo,
    float* __restrict__ gb2)
{
    if (blockIdx.x < 512) {
        int t = (blockIdx.x & 255) * 256 + threadIdx.x;
        const int lane = t & 63;
        const int kg   = lane >> 4;
        const int row  = lane & 15;
        if (blockIdx.x < 256) {
            const int ni = (t >> 6) & 31;
            const int ks = (t >> 11) & 7;
            const int e  = t >> 14;
            const int n  = ni * 16 + row;
            const int k0 = ks * 32 + kg * 8;
            short8 o;
            #pragma unroll
            for (int j = 0; j < 8; ++j)
                o[j] = (short)f2bf(w1[((size_t)e * HD + k0 + j) * FF + n]);
            *reinterpret_cast<short8*>(&w1p[(size_t)(((e*8 + ks)*32 + ni)*64 + lane) * 8]) = o;
        } else {
            const int ni = (t >> 6) & 15;
            const int ks = (t >> 10) & 15;
            const int e  = t >> 14;
            const int n  = ni * 16 + row;
            const int k0 = ks * 32 + kg * 8;
            short8 o;
            #pragma unroll
            for (int j = 0; j < 8; ++j)
                o[j] = (short)f2bf(w2[((size_t)e * FF + k0 + j) * HD + n]);
            *reinterpret_cast<short8*>(&w2p[(size_t)(((e*16 + ks)*16 + ni)*64 + lane) * 8]) = o;
        }
        return;
    }
    const int slot = (blockIdx.x - 512) * 256 + threadIdx.x;
    const int lane = slot & 63;
    const int kg   = lane >> 4;
    const int row  = lane & 15;
    if (slot < 1024) {
        const int f = slot >> 6, ks = f >> 1, ni = f & 1;
        const int n = ni * 16 + row;
        f16x8 hi, lo;
        #pragma unroll
        for (int j = 0; j < 8; ++j) {
            int k = ks * 32 + kg * 8 + j;
            F16Pair p = split16(ln_g[k] * geom_w[k * DG + n]);
            hi[j] = p.hi; lo[j] = p.lo;
        }
        *reinterpret_cast<f16x8*>(&wg_hi[(size_t)slot * 8]) = hi;
        *reinterpret_cast<f16x8*>(&wg_lo[(size_t)slot * 8]) = lo;
    } else if (slot < 1536) {
        const int s = slot - 1024;
        const int f = s >> 6, ks = f >> 2, ni = f & 3;
        const int n = ni * 16 + row;
        f16x8 hi, lo;
        #pragma unroll
        for (int j = 0; j < 8; ++j) {
            int k = ks * 32 + kg * 8 + j;
            F16Pair p = split16(fuse_w[k * FM + n]);
            hi[j] = p.hi; lo[j] = p.lo;
        }
        *reinterpret_cast<f16x8*>(&wf_hi[(size_t)s * 8]) = hi;
        *reinterpret_cast<f16x8*>(&wf_lo[(size_t)s * 8]) = lo;
    } else if (slot < 1664) {
        const int s = slot - 1536;
        const int ks = s >> 6;
        f16x8 hi, lo;
        #pragma unroll
        for (int j = 0; j < 8; ++j) {
            int k = ks * 32 + kg * 8 + j;
            F16Pair p = split16((row < NE) ? router_w[k * NE + row] : 0.f);
            hi[j] = p.hi; lo[j] = p.lo;
        }
        *reinterpret_cast<f16x8*>(&wr_hi[(size_t)s * 8]) = hi;
        *reinterpret_cast<f16x8*>(&wr_lo[(size_t)s * 8]) = lo;
    } else if (slot < 1696) {
        const int n = slot - 1664;   // 0..31
        float acc = geom_b[n];
        for (int k = 0; k < HD; ++k) acc += ln_b[k] * geom_w[k * DG + n];
        gb2[n] = acc;
    }
}

// ---------------------------------------------------------------------------
// Router v3 (MFMA + fused bucketing): as round-6 router2 plus direct order
// write into per-expert region order[e*N_TOK + base + rank]; no top_idx.
// ---------------------------------------------------------------------------
__global__ __launch_bounds__(256) void router3_kernel(
    const float* __restrict__ h, const float* __restrict__ tok_emb,
    const _Float16* __restrict__ wg_hi, const _Float16* __restrict__ wg_lo,
    const _Float16* __restrict__ wf_hi, const _Float16* __restrict__ wf_lo,
    const _Float16* __restrict__ wr_hi, const _Float16* __restrict__ wr_lo,
    const float* __restrict__ gb2, const float* __restrict__ fuse_b,
    const float* __restrict__ router_b,
    float* __restrict__ top_prob, int* __restrict__ order,
    int* __restrict__ counts, float* __restrict__ importance)
{
    __shared__ __align__(16) _Float16 sg_hi[4][16][40], sg_lo[4][16][40];
    __shared__ __align__(16) _Float16 su_hi[4][16][72], su_lo[4][16][72];
    __shared__ __align__(16) float    s_lg[4][16][4];
    __shared__ float s_imp[NE];
    __shared__ int   s_cnt[NE];
    __shared__ int   s_base[NE];

    const int tid  = threadIdx.x;
    const int wv   = tid >> 6;
    const int lane = tid & 63;
    const int kg   = lane >> 4;
    const int row  = lane & 15;
    const int tok  = blockIdx.x * 64 + wv * 16 + row;

    if (tid < NE) { s_imp[tid] = 0.f; s_cnt[tid] = 0; }
    __syncthreads();

    const float* hrow = h + (size_t)tok * HD;
    float s1 = 0.f, s2 = 0.f;
    #pragma unroll
    for (int ks = 0; ks < 8; ++ks) {
        float4 x0 = *reinterpret_cast<const float4*>(hrow + ks * 32 + kg * 8);
        float4 x1 = *reinterpret_cast<const float4*>(hrow + ks * 32 + kg * 8 + 4);
        s1 += (x0.x + x0.y) + (x0.z + x0.w) + (x1.x + x1.y) + (x1.z + x1.w);
        s2 += x0.x*x0.x + x0.y*x0.y + x0.z*x0.z + x0.w*x0.w
            + x1.x*x1.x + x1.y*x1.y + x1.z*x1.z + x1.w*x1.w;
    }
    s1 += __shfl_xor(s1, 16); s1 += __shfl_xor(s1, 32);
    s2 += __shfl_xor(s2, 16); s2 += __shfl_xor(s2, 32);
    const float mu   = s1 * (1.0f / HD);
    const float var  = s2 * (1.0f / HD) - mu * mu;
    const float rstd = rsqrtf(var + 1e-5f);

    f16x8 ahi[8], alo[8];
    #pragma unroll
    for (int ks = 0; ks < 8; ++ks) {
        float4 x0 = *reinterpret_cast<const float4*>(hrow + ks * 32 + kg * 8);
        float4 x1 = *reinterpret_cast<const float4*>(hrow + ks * 32 + kg * 8 + 4);
        float v[8] = {x0.x, x0.y, x0.z, x0.w, x1.x, x1.y, x1.z, x1.w};
        #pragma unroll
        for (int j = 0; j < 8; ++j) {
            F16Pair p = split16((v[j] - mu) * rstd);
            ahi[ks][j] = p.hi; alo[ks][j] = p.lo;
        }
    }

    const f16x8* WGH = reinterpret_cast<const f16x8*>(wg_hi);
    const f16x8* WGL = reinterpret_cast<const f16x8*>(wg_lo);
    f32x4 accg[2];
    #pragma unroll
    for (int ni = 0; ni < 2; ++ni) {
        float bb = gb2[ni * 16 + row];
        accg[ni] = (f32x4){bb, bb, bb, bb};
    }
    #pragma unroll
    for (int ks = 0; ks < 8; ++ks) {
        #pragma unroll
        for (int ni = 0; ni < 2; ++ni) {
            f16x8 bh = WGH[(ks * 2 + ni) * 64 + lane];
            f16x8 bl = WGL[(ks * 2 + ni) * 64 + lane];
            accg[ni] = __builtin_amdgcn_mfma_f32_16x16x32_f16(ahi[ks], bh, accg[ni], 0, 0, 0);
            accg[ni] = __builtin_amdgcn_mfma_f32_16x16x32_f16(alo[ks], bh, accg[ni], 0, 0, 0);
            accg[ni] = __builtin_amdgcn_mfma_f32_16x16x32_f16(ahi[ks], bl, accg[ni], 0, 0, 0);
        }
    }
    #pragma unroll
    for (int ni = 0; ni < 2; ++ni)
        #pragma unroll
        for (int r = 0; r < 4; ++r) {
            F16Pair p = split16(gelu_f(accg[ni][r]));
            sg_hi[wv][kg * 4 + r][ni * 16 + row] = p.hi;
            sg_lo[wv][kg * 4 + r][ni * 16 + row] = p.lo;
        }

    f16x8 a2h[2], a2l[2];
    {
        const float* terow = tok_emb + (size_t)tok * DS;
        float4 x0 = *reinterpret_cast<const float4*>(terow + kg * 8);
        float4 x1 = *reinterpret_cast<const float4*>(terow + kg * 8 + 4);
        float v[8] = {x0.x, x0.y, x0.z, x0.w, x1.x, x1.y, x1.z, x1.w};
        #pragma unroll
        for (int j = 0; j < 8; ++j) {
            F16Pair p = split16(v[j]);
            a2h[0][j] = p.hi; a2l[0][j] = p.lo;
        }
        a2h[1] = *reinterpret_cast<const f16x8*>(&sg_hi[wv][row][kg * 8]);
        a2l[1] = *reinterpret_cast<const f16x8*>(&sg_lo[wv][row][kg * 8]);
    }
    const f16x8* WFH = reinterpret_cast<const f16x8*>(wf_hi);
    const f16x8* WFL = reinterpret_cast<const f16x8*>(wf_lo);
    f32x4 accf[4];
    #pragma unroll
    for (int ni = 0; ni < 4; ++ni) {
        float bb = fuse_b[ni * 16 + row];
        accf[ni] = (f32x4){bb, bb, bb, bb};
    }
    #pragma unroll
    for (int ks = 0; ks < 2; ++ks) {
        #pragma unroll
        for (int ni = 0; ni < 4; ++ni) {
            f16x8 bh = WFH[(ks * 4 + ni) * 64 + lane];
            f16x8 bl = WFL[(ks * 4 + ni) * 64 + lane];
            accf[ni] = __builtin_amdgcn_mfma_f32_16x16x32_f16(a2h[ks], bh, accf[ni], 0, 0, 0);
            accf[ni] = __builtin_amdgcn_mfma_f32_16x16x32_f16(a2l[ks], bh, accf[ni], 0, 0, 0);
            accf[ni] = __builtin_amdgcn_mfma_f32_16x16x32_f16(a2h[ks], bl, accf[ni], 0, 0, 0);
        }
    }
    #pragma unroll
    for (int ni = 0; ni < 4; ++ni)
        #pragma unroll
        for (int r = 0; r < 4; ++r) {
            F16Pair p = split16(gelu_f(accf[ni][r]));
            su_hi[wv][kg * 4 + r][ni * 16 + row] = p.hi;
            su_lo[wv][kg * 4 + r][ni * 16 + row] = p.lo;
        }

    const f16x8* WRH = reinterpret_cast<const f16x8*>(wr_hi);
    const f16x8* WRL = reinterpret_cast<const f16x8*>(wr_lo);
    f32x4 accl = (f32x4){0.f, 0.f, 0.f, 0.f};
    #pragma unroll
    for (int ks = 0; ks < 2; ++ks) {
        f16x8 a3h = *reinterpret_cast<const f16x8*>(&su_hi[wv][row][ks * 32 + kg * 8]);
        f16x8 a3l = *reinterpret_cast<const f16x8*>(&su_lo[wv][row][ks * 32 + kg * 8]);
        f16x8 bh = WRH[ks * 64 + lane];
        f16x8 bl = WRL[ks * 64 + lane];
        accl = __builtin_amdgcn_mfma_f32_16x16x32_f16(a3h, bh, accl, 0, 0, 0);
        accl = __builtin_amdgcn_mfma_f32_16x16x32_f16(a3l, bh, accl, 0, 0, 0);
        accl = __builtin_amdgcn_mfma_f32_16x16x32_f16(a3h, bl, accl, 0, 0, 0);
    }
    if (row < NE) {
        float rb = router_b[row];
        #pragma unroll
        for (int r = 0; r < 4; ++r)
            s_lg[wv][kg * 4 + r][row] = accl[r] + rb;
    }
    __syncthreads();

    // ---- softmax/argmax + local rank (lanes 0..15, one token each) ----
    int bi = 0, rk = 0, gt = 0;
    if (lane < 16) {
        float4 lg = *reinterpret_cast<const float4*>(&s_lg[wv][lane][0]);
        float m  = fmaxf(fmaxf(lg.x, lg.y), fmaxf(lg.z, lg.w));
        float e0 = expf(lg.x - m), e1 = expf(lg.y - m),
              e2 = expf(lg.z - m), e3 = expf(lg.w - m);
        float inv = 1.0f / (e0 + e1 + e2 + e3);
        float p0 = e0 * inv, p1 = e1 * inv, p2 = e2 * inv, p3 = e3 * inv;
        float bp = p0;
        if (p1 > bp) { bp = p1; bi = 1; }
        if (p2 > bp) { bp = p2; bi = 2; }
        if (p3 > bp) { bp = p3; bi = 3; }
        gt = blockIdx.x * 64 + wv * 16 + lane;
        top_prob[gt] = bp;
        rk = atomicAdd(&s_cnt[bi], 1);
        atomicAdd(&s_imp[0], p0); atomicAdd(&s_imp[1], p1);
        atomicAdd(&s_imp[2], p2); atomicAdd(&s_imp[3], p3);
    }
    __syncthreads();
    if (tid < NE) {
        s_base[tid] = atomicAdd(&counts[tid], s_cnt[tid]);  // reserve + count
        atomicAdd(&importance[tid], s_imp[tid]);
    }
    __syncthreads();
    if (lane < 16)
        order[bi * N_TOK + s_base[bi] + rk] = gt;
}

// ---------------------------------------------------------------------------
// Expert FFN v4: round-7 structure (operand-swapped, two-pass FF) with
// tanh-GELU; last block computes lb_loss (replaces scan kernel).
// ---------------------------------------------------------------------------
__global__ __launch_bounds__(512, 4) void expert_mfma_kernel(
    const float* __restrict__ h,
    const unsigned short* __restrict__ w1p,
    const unsigned short* __restrict__ w2p,
    const float* __restrict__ b1, const float* __restrict__ b2,
    const float* __restrict__ top_prob,
    const int* __restrict__ order, const int* __restrict__ counts,
    const float* __restrict__ importance, float* __restrict__ out)
{
    __shared__ __align__(16) unsigned short sh_h[8 * 4 * 512];   // 32 KB
    __shared__ __align__(16) unsigned short sh_a[8 * 4 * 512];   // 32 KB
    __shared__ int s_tok[MT];

    const int tid = threadIdx.x;

    if (blockIdx.x == N_TOK / MT + NE) {      // lb block
        if (tid == 0) {
            double num = (double)importance[0] * counts[0] +
                         (double)importance[1] * counts[1] +
                         (double)importance[2] * counts[2] +
                         (double)importance[3] * counts[3];
            out[(size_t)N_TOK * HD] =
                (float)((double)NE * num / ((double)N_TOK * (double)N_TOK + 1e-8));
        }
        return;
    }

    int c = blockIdx.x, e;
    for (e = 0; e < NE; ++e) {
        int nch = (counts[e] + MT - 1) / MT;
        if (c < nch) break;
        c -= nch;
    }
    if (e >= NE) return;
    const int cnt  = counts[e];
    const int base = e * N_TOK + c * MT;
    const int nt   = min(MT, cnt - c * MT);

    if (tid < MT) s_tok[tid] = (tid < nt) ? order[base + tid] : -1;
    __syncthreads();

    #pragma unroll
    for (int it = 0; it < 4; ++it) {
        int chunk = tid + it * 512;
        int tr = chunk >> 5, q = chunk & 31;
        int t = s_tok[tr];
        float4 v0 = make_float4(0.f,0.f,0.f,0.f), v1 = v0;
        if (t >= 0) {
            const float* p = &h[(size_t)t * HD + q * 8];
            v0 = *reinterpret_cast<const float4*>(p);
            v1 = *reinterpret_cast<const float4*>(p + 4);
        }
        short8 o;
        o[0] = (short)f2bf(v0.x); o[1] = (short)f2bf(v0.y);
        o[2] = (short)f2bf(v0.z); o[3] = (short)f2bf(v0.w);
        o[4] = (short)f2bf(v1.x); o[5] = (short)f2bf(v1.y);
        o[6] = (short)f2bf(v1.z); o[7] = (short)f2bf(v1.w);
        int ks = q >> 2, kg = q & 3, mi = tr >> 4, row = tr & 15;
        *reinterpret_cast<short8*>(&sh_h[((ks*4 + kg? (ks*4+mi) : (ks*4+mi))*0 + ((ks*4 + mi)*64 + kg*16 + row)) * 8]) = o;
    }
    __syncthreads();

    const int lane  = tid & 63;
    const int wv    = tid >> 6;
    const int row15 = lane & 15;
    const int kg    = lane >> 4;

    const unsigned short* W1 = w1p + (size_t)e * 8 * 32 * 512;
    const unsigned short* W2 = w2p + (size_t)e * 16 * 16 * 512;

    f32x4 acc2[2][4];
    #pragma unroll
    for (int ni = 0; ni < 2; ++ni) {
        f32x4 bb = *reinterpret_cast<const f32x4*>(&b2[e * HD + wv * 32 + ni * 16 + kg * 4]);
        #pragma unroll
        for (int mi = 0; mi < 4; ++mi) acc2[ni][mi] = bb;
    }

    #pragma unroll
    for (int p = 0; p < 2; ++p) {
        f32x4 acc1[2][4];
        #pragma unroll
        for (int ni = 0; ni < 2; ++ni) {
            f32x4 bb = *reinterpret_cast<const f32x4*>(
                &b1[e * FF + p * 256 + wv * 32 + ni * 16 + kg * 4]);
            #pragma unroll
            for (int mi = 0; mi < 4; ++mi) acc1[ni][mi] = bb;
        }
        #pragma unroll
        for (int ks = 0; ks < 8; ++ks) {
            short8 bh[4];
            #pragma unroll
            for (int mi = 0; mi < 4; ++mi)
                bh[mi] = *reinterpret_cast<const short8*>(&sh_h[((ks*4 + mi)*64 + lane) * 8]);
            #pragma unroll
            for (int ni = 0; ni < 2; ++ni) {
                short8 aw = *reinterpret_cast<const short8*>(
                    &W1[(size_t)((ks*32 + p*16 + wv*2 + ni)*64 + lane) * 8]);
                #pragma unroll
                for (int mi = 0; mi < 4; ++mi)
                    acc1[ni][mi] = __builtin_amdgcn_mfma_f32_16x16x32_bf16(aw, bh[mi], acc1[ni][mi], 0, 0, 0);
            }
        }
        if (p == 1) __syncthreads();

        #pragma unroll
        for (int ni = 0; ni < 2; ++ni) {
            const int kgp = ni * 2 + (kg >> 1);
            #pragma unroll
            for (int mi = 0; mi < 4; ++mi) {
                ushort4 pk;
                pk.x = f2bf(gelu_t(acc1[ni][mi][0]));
                pk.y = f2bf(gelu_t(acc1[ni][mi][1]));
                pk.z = f2bf(gelu_t(acc1[ni][mi][2]));
                pk.w = f2bf(gelu_t(acc1[ni][mi][3]));
                *reinterpret_cast<ushort4*>(
                    &sh_a[(((wv*4 + mi)*64 + kgp*16 + row15) * 8 + (kg & 1) * 4)]) = pk;
            }
        }
        __syncthreads();

        #pragma unroll
        for (int l = 0; l < 8; ++l) {
            short8 ba[4];
            #pragma unroll
            for (int mi = 0; mi < 4; ++mi)
                ba[mi] = *reinterpret_cast<const short8*>(&sh_a[((l*4 + mi)*64 + lane) * 8]);
            #pragma unroll
            for (int ni = 0; ni < 2; ++ni) {
                short8 aw = *reinterpret_cast<const short8*>(
                    &W2[(size_t)(((p*8 + l)*16 + wv*2 + ni)*64 + lane) * 8]);
                #pragma unroll
                for (int mi = 0; mi < 4; ++mi)
                    acc2[ni][mi] = __builtin_amdgcn_mfma_f32_16x16x32_bf16(aw, ba[mi], acc2[ni][mi], 0, 0, 0);
            }
        }
    }

    #pragma unroll
    for (int mi = 0; mi < 4; ++mi) {
        int gt = s_tok[mi * 16 + row15];
        if (gt < 0) continue;
        float tp = 0.5f * top_prob[gt];
        #pragma unroll
        for (int ni = 0; ni < 2; ++ni) {
            int nb = wv * 32 + ni * 16 + kg * 4;
            float4 res = *reinterpret_cast<const float4*>(&h[(size_t)gt * HD + nb]);
            float4 o;
            o.x = res.x + tp * acc2[ni][mi][0];
            o.y = res.y + tp * acc2[ni][mi][1];
            o.z = res.z + tp * acc2[ni][mi][2];
            o.w = res.w + tp * acc2[ni][mi][3];
            *reinterpret_cast<float4*>(&out[(size_t)gt * HD + nb]) = o;
        }
    }
}

// ---------------------------------------------------------------------------
extern "C" void kernel_launch(void* const* d_in, const int* in_sizes, int n_in,
                              void* d_out, int out_size, void* d_ws, size_t ws_size,
                              hipStream_t stream)
{
    const float* h        = (const float*)d_in[0];
    const float* tok_emb  = (const float*)d_in[1];
    /* d_in[2] = is_mask: all zeros, unused by the reference math */
    const float* ln_g     = (const float*)d_in[3];
    const float* ln_b     = (const float*)d_in[4];
    const float* geom_w   = (const float*)d_in[5];
    const float* geom_b   = (const float*)d_in[6];
    const float* fuse_w   = (const float*)d_in[7];
    const float* fuse_b   = (const float*)d_in[8];
    const float* router_w = (const float*)d_in[9];
    const float* router_b = (const float*)d_in[10];
    const float* w1       = (const float*)d_in[11];
    const float* b1       = (const float*)d_in[12];
    const float* w2       = (const float*)d_in[13];
    const float* b2       = (const float*)d_in[14];
    float* out = (float*)d_out;

    // workspace layout (4B word units from d_ws)
    int*   counts     = (int*)d_ws;                        // [4]
    float* importance = (float*)d_ws + 4;                  // [4]
    float* top_prob   = (float*)d_ws + 64;                 // [N]
    int*   order      = (int*)d_ws + 64 + N_TOK;           // [4*N] regions
    unsigned short* w1p = (unsigned short*)((int*)d_ws + 64 + 5 * N_TOK); // 1MB
    unsigned short* w2p = w1p + (size_t)NE * FF * HD;                     // 1MB
    _Float16* wg_hi = (_Float16*)(w2p + (size_t)NE * FF * HD);
    _Float16* wg_lo = wg_hi + 8192;
    _Float16* wf_hi = wg_lo + 8192;
    _Float16* wf_lo = wf_hi + 4096;
    _Float16* wr_hi = wf_lo + 4096;
    _Float16* wr_lo = wr_hi + 1024;
    float*    gb2   = (float*)(wr_lo + 1024);              // [32]

    hipMemsetAsync(d_ws, 0, 64 * sizeof(int), stream);

    prep_all_kernel<<<519, 256, 0, stream>>>(
        w1, w2, w1p, w2p,
        geom_w, geom_b, ln_g, ln_b, fuse_w, router_w,
        wg_hi, wg_lo, wf_hi, wf_lo, wr_hi, wr_lo, gb2);

    router3_kernel<<<N_TOK / 64, 256, 0, stream>>>(
        h, tok_emb, wg_hi, wg_lo, wf_hi, wf_lo, wr_hi, wr_lo,
        gb2, fuse_b, router_b, top_prob, order, counts, importance);

    expert_mfma_kernel<<<N_TOK / MT + NE + 1, 512, 0, stream>>>(
        h, w1p, w2p, b1, b2, top_prob, order, counts, importance, out);
}

// Round 9
// 233.644 us; speedup vs baseline: 8.3078x; 1.0708x over previous
//
#include <hip/hip_runtime.h>
#include <hip/hip_bf16.h>
#include <math.h>

#define N_TOK 131072
#define HD    256
#define DS    32
#define DG    32
#define FM    64
#define NE    4
#define FF    512
#define MT    64   // tokens per expert block (8 waves, 512 threads)

typedef short    short8 __attribute__((ext_vector_type(8)));
typedef _Float16 f16x8  __attribute__((ext_vector_type(8)));
typedef float    f32x4  __attribute__((ext_vector_type(4)));

struct F16Pair { _Float16 hi, lo; };

__device__ __forceinline__ float gelu_f(float x) {        // exact erf
    return 0.5f * x * (1.0f + erff(x * 0.70710678118654752f));
}
__device__ __forceinline__ unsigned short f2bf(float x) {
    union { __hip_bfloat16 b; unsigned short u; } cv;
    cv.b = __float2bfloat16(x);
    return cv.u;
}
__device__ __forceinline__ F16Pair split16(float v) {
    F16Pair p;
    p.hi = (_Float16)v;
    p.lo = (_Float16)(v - (float)p.hi);
    return p;
}

// ---------------------------------------------------------------------------
// Prep (fused): blocks 0..511 repack expert weights (frag-ordered bf16);
// blocks 512..518 build router fp16 hi/lo tables + folded gb2.
// ---------------------------------------------------------------------------
__global__ __launch_bounds__(256) void prep_all_kernel(
    const float* __restrict__ w1, const float* __restrict__ w2,
    unsigned short* __restrict__ w1p, unsigned short* __restrict__ w2p,
    const float* __restrict__ geom_w, const float* __restrict__ geom_b,
    const float* __restrict__ ln_g, const float* __restrict__ ln_b,
    const float* __restrict__ fuse_w, const float* __restrict__ router_w,
    _Float16* __restrict__ wg_hi, _Float16* __restrict__ wg_lo,
    _Float16* __restrict__ wf_hi, _Float16* __restrict__ wf_lo,
    _Float16* __restrict__ wr_hi, _Float16* __restrict__ wr_lo,
    float* __restrict__ gb2)
{
    if (blockIdx.x < 512) {
        int t = (blockIdx.x & 255) * 256 + threadIdx.x;
        const int lane = t & 63;
        const int kg   = lane >> 4;
        const int row  = lane & 15;
        if (blockIdx.x < 256) {
            const int ni = (t >> 6) & 31;
            const int ks = (t >> 11) & 7;
            const int e  = t >> 14;
            const int n  = ni * 16 + row;
            const int k0 = ks * 32 + kg * 8;
            short8 o;
            #pragma unroll
            for (int j = 0; j < 8; ++j)
                o[j] = (short)f2bf(w1[((size_t)e * HD + k0 + j) * FF + n]);
            *reinterpret_cast<short8*>(&w1p[(size_t)(((e*8 + ks)*32 + ni)*64 + lane) * 8]) = o;
        } else {
            const int ni = (t >> 6) & 15;
            const int ks = (t >> 10) & 15;
            const int e  = t >> 14;
            const int n  = ni * 16 + row;
            const int k0 = ks * 32 + kg * 8;
            short8 o;
            #pragma unroll
            for (int j = 0; j < 8; ++j)
                o[j] = (short)f2bf(w2[((size_t)e * FF + k0 + j) * HD + n]);
            *reinterpret_cast<short8*>(&w2p[(size_t)(((e*16 + ks)*16 + ni)*64 + lane) * 8]) = o;
        }
        return;
    }
    const int slot = (blockIdx.x - 512) * 256 + threadIdx.x;
    const int lane = slot & 63;
    const int kg   = lane >> 4;
    const int row  = lane & 15;
    if (slot < 1024) {
        const int f = slot >> 6, ks = f >> 1, ni = f & 1;
        const int n = ni * 16 + row;
        f16x8 hi, lo;
        #pragma unroll
        for (int j = 0; j < 8; ++j) {
            int k = ks * 32 + kg * 8 + j;
            F16Pair p = split16(ln_g[k] * geom_w[k * DG + n]);
            hi[j] = p.hi; lo[j] = p.lo;
        }
        *reinterpret_cast<f16x8*>(&wg_hi[(size_t)slot * 8]) = hi;
        *reinterpret_cast<f16x8*>(&wg_lo[(size_t)slot * 8]) = lo;
    } else if (slot < 1536) {
        const int s = slot - 1024;
        const int f = s >> 6, ks = f >> 2, ni = f & 3;
        const int n = ni * 16 + row;
        f16x8 hi, lo;
        #pragma unroll
        for (int j = 0; j < 8; ++j) {
            int k = ks * 32 + kg * 8 + j;
            F16Pair p = split16(fuse_w[k * FM + n]);
            hi[j] = p.hi; lo[j] = p.lo;
        }
        *reinterpret_cast<f16x8*>(&wf_hi[(size_t)s * 8]) = hi;
        *reinterpret_cast<f16x8*>(&wf_lo[(size_t)s * 8]) = lo;
    } else if (slot < 1664) {
        const int s = slot - 1536;
        const int ks = s >> 6;
        f16x8 hi, lo;
        #pragma unroll
        for (int j = 0; j < 8; ++j) {
            int k = ks * 32 + kg * 8 + j;
            F16Pair p = split16((row < NE) ? router_w[k * NE + row] : 0.f);
            hi[j] = p.hi; lo[j] = p.lo;
        }
        *reinterpret_cast<f16x8*>(&wr_hi[(size_t)s * 8]) = hi;
        *reinterpret_cast<f16x8*>(&wr_lo[(size_t)s * 8]) = lo;
    } else if (slot < 1696) {
        const int n = slot - 1664;   // 0..31
        float acc = geom_b[n];
        for (int k = 0; k < HD; ++k) acc += ln_b[k] * geom_w[k * DG + n];
        gb2[n] = acc;
    }
}

// ---------------------------------------------------------------------------
// Router v3 (MFMA + fused bucketing) — unchanged from round 8 (verified).
// ---------------------------------------------------------------------------
__global__ __launch_bounds__(256) void router3_kernel(
    const float* __restrict__ h, const float* __restrict__ tok_emb,
    const _Float16* __restrict__ wg_hi, const _Float16* __restrict__ wg_lo,
    const _Float16* __restrict__ wf_hi, const _Float16* __restrict__ wf_lo,
    const _Float16* __restrict__ wr_hi, const _Float16* __restrict__ wr_lo,
    const float* __restrict__ gb2, const float* __restrict__ fuse_b,
    const float* __restrict__ router_b,
    float* __restrict__ top_prob, int* __restrict__ order,
    int* __restrict__ counts, float* __restrict__ importance)
{
    __shared__ __align__(16) _Float16 sg_hi[4][16][40], sg_lo[4][16][40];
    __shared__ __align__(16) _Float16 su_hi[4][16][72], su_lo[4][16][72];
    __shared__ __align__(16) float    s_lg[4][16][4];
    __shared__ float s_imp[NE];
    __shared__ int   s_cnt[NE];
    __shared__ int   s_base[NE];

    const int tid  = threadIdx.x;
    const int wv   = tid >> 6;
    const int lane = tid & 63;
    const int kg   = lane >> 4;
    const int row  = lane & 15;
    const int tok  = blockIdx.x * 64 + wv * 16 + row;

    if (tid < NE) { s_imp[tid] = 0.f; s_cnt[tid] = 0; }
    __syncthreads();

    const float* hrow = h + (size_t)tok * HD;
    float s1 = 0.f, s2 = 0.f;
    #pragma unroll
    for (int ks = 0; ks < 8; ++ks) {
        float4 x0 = *reinterpret_cast<const float4*>(hrow + ks * 32 + kg * 8);
        float4 x1 = *reinterpret_cast<const float4*>(hrow + ks * 32 + kg * 8 + 4);
        s1 += (x0.x + x0.y) + (x0.z + x0.w) + (x1.x + x1.y) + (x1.z + x1.w);
        s2 += x0.x*x0.x + x0.y*x0.y + x0.z*x0.z + x0.w*x0.w
            + x1.x*x1.x + x1.y*x1.y + x1.z*x1.z + x1.w*x1.w;
    }
    s1 += __shfl_xor(s1, 16); s1 += __shfl_xor(s1, 32);
    s2 += __shfl_xor(s2, 16); s2 += __shfl_xor(s2, 32);
    const float mu   = s1 * (1.0f / HD);
    const float var  = s2 * (1.0f / HD) - mu * mu;
    const float rstd = rsqrtf(var + 1e-5f);

    f16x8 ahi[8], alo[8];
    #pragma unroll
    for (int ks = 0; ks < 8; ++ks) {
        float4 x0 = *reinterpret_cast<const float4*>(hrow + ks * 32 + kg * 8);
        float4 x1 = *reinterpret_cast<const float4*>(hrow + ks * 32 + kg * 8 + 4);
        float v[8] = {x0.x, x0.y, x0.z, x0.w, x1.x, x1.y, x1.z, x1.w};
        #pragma unroll
        for (int j = 0; j < 8; ++j) {
            F16Pair p = split16((v[j] - mu) * rstd);
            ahi[ks][j] = p.hi; alo[ks][j] = p.lo;
        }
    }

    const f16x8* WGH = reinterpret_cast<const f16x8*>(wg_hi);
    const f16x8* WGL = reinterpret_cast<const f16x8*>(wg_lo);
    f32x4 accg[2];
    #pragma unroll
    for (int ni = 0; ni < 2; ++ni) {
        float bb = gb2[ni * 16 + row];
        accg[ni] = (f32x4){bb, bb, bb, bb};
    }
    #pragma unroll
    for (int ks = 0; ks < 8; ++ks) {
        #pragma unroll
        for (int ni = 0; ni < 2; ++ni) {
            f16x8 bh = WGH[(ks * 2 + ni) * 64 + lane];
            f16x8 bl = WGL[(ks * 2 + ni) * 64 + lane];
            accg[ni] = __builtin_amdgcn_mfma_f32_16x16x32_f16(ahi[ks], bh, accg[ni], 0, 0, 0);
            accg[ni] = __builtin_amdgcn_mfma_f32_16x16x32_f16(alo[ks], bh, accg[ni], 0, 0, 0);
            accg[ni] = __builtin_amdgcn_mfma_f32_16x16x32_f16(ahi[ks], bl, accg[ni], 0, 0, 0);
        }
    }
    #pragma unroll
    for (int ni = 0; ni < 2; ++ni)
        #pragma unroll
        for (int r = 0; r < 4; ++r) {
            F16Pair p = split16(gelu_f(accg[ni][r]));
            sg_hi[wv][kg * 4 + r][ni * 16 + row] = p.hi;
            sg_lo[wv][kg * 4 + r][ni * 16 + row] = p.lo;
        }

    f16x8 a2h[2], a2l[2];
    {
        const float* terow = tok_emb + (size_t)tok * DS;
        float4 x0 = *reinterpret_cast<const float4*>(terow + kg * 8);
        float4 x1 = *reinterpret_cast<const float4*>(terow + kg * 8 + 4);
        float v[8] = {x0.x, x0.y, x0.z, x0.w, x1.x, x1.y, x1.z, x1.w};
        #pragma unroll
        for (int j = 0; j < 8; ++j) {
            F16Pair p = split16(v[j]);
            a2h[0][j] = p.hi; a2l[0][j] = p.lo;
        }
        a2h[1] = *reinterpret_cast<const f16x8*>(&sg_hi[wv][row][kg * 8]);
        a2l[1] = *reinterpret_cast<const f16x8*>(&sg_lo[wv][row][kg * 8]);
    }
    const f16x8* WFH = reinterpret_cast<const f16x8*>(wf_hi);
    const f16x8* WFL = reinterpret_cast<const f16x8*>(wf_lo);
    f32x4 accf[4];
    #pragma unroll
    for (int ni = 0; ni < 4; ++ni) {
        float bb = fuse_b[ni * 16 + row];
        accf[ni] = (f32x4){bb, bb, bb, bb};
    }
    #pragma unroll
    for (int ks = 0; ks < 2; ++ks) {
        #pragma unroll
        for (int ni = 0; ni < 4; ++ni) {
            f16x8 bh = WFH[(ks * 4 + ni) * 64 + lane];
            f16x8 bl = WFL[(ks * 4 + ni) * 64 + lane];
            accf[ni] = __builtin_amdgcn_mfma_f32_16x16x32_f16(a2h[ks], bh, accf[ni], 0, 0, 0);
            accf[ni] = __builtin_amdgcn_mfma_f32_16x16x32_f16(a2l[ks], bh, accf[ni], 0, 0, 0);
            accf[ni] = __builtin_amdgcn_mfma_f32_16x16x32_f16(a2h[ks], bl, accf[ni], 0, 0, 0);
        }
    }
    #pragma unroll
    for (int ni = 0; ni < 4; ++ni)
        #pragma unroll
        for (int r = 0; r < 4; ++r) {
            F16Pair p = split16(gelu_f(accf[ni][r]));
            su_hi[wv][kg * 4 + r][ni * 16 + row] = p.hi;
            su_lo[wv][kg * 4 + r][ni * 16 + row] = p.lo;
        }

    const f16x8* WRH = reinterpret_cast<const f16x8*>(wr_hi);
    const f16x8* WRL = reinterpret_cast<const f16x8*>(wr_lo);
    f32x4 accl = (f32x4){0.f, 0.f, 0.f, 0.f};
    #pragma unroll
    for (int ks = 0; ks < 2; ++ks) {
        f16x8 a3h = *reinterpret_cast<const f16x8*>(&su_hi[wv][row][ks * 32 + kg * 8]);
        f16x8 a3l = *reinterpret_cast<const f16x8*>(&su_lo[wv][row][ks * 32 + kg * 8]);
        f16x8 bh = WRH[ks * 64 + lane];
        f16x8 bl = WRL[ks * 64 + lane];
        accl = __builtin_amdgcn_mfma_f32_16x16x32_f16(a3h, bh, accl, 0, 0, 0);
        accl = __builtin_amdgcn_mfma_f32_16x16x32_f16(a3l, bh, accl, 0, 0, 0);
        accl = __builtin_amdgcn_mfma_f32_16x16x32_f16(a3h, bl, accl, 0, 0, 0);
    }
    if (row < NE) {
        float rb = router_b[row];
        #pragma unroll
        for (int r = 0; r < 4; ++r)
            s_lg[wv][kg * 4 + r][row] = accl[r] + rb;
    }
    __syncthreads();

    int bi = 0, rk = 0, gt = 0;
    if (lane < 16) {
        float4 lg = *reinterpret_cast<const float4*>(&s_lg[wv][lane][0]);
        float m  = fmaxf(fmaxf(lg.x, lg.y), fmaxf(lg.z, lg.w));
        float e0 = expf(lg.x - m), e1 = expf(lg.y - m),
              e2 = expf(lg.z - m), e3 = expf(lg.w - m);
        float inv = 1.0f / (e0 + e1 + e2 + e3);
        float p0 = e0 * inv, p1 = e1 * inv, p2 = e2 * inv, p3 = e3 * inv;
        float bp = p0;
        if (p1 > bp) { bp = p1; bi = 1; }
        if (p2 > bp) { bp = p2; bi = 2; }
        if (p3 > bp) { bp = p3; bi = 3; }
        gt = blockIdx.x * 64 + wv * 16 + lane;
        top_prob[gt] = bp;
        rk = atomicAdd(&s_cnt[bi], 1);
        atomicAdd(&s_imp[0], p0); atomicAdd(&s_imp[1], p1);
        atomicAdd(&s_imp[2], p2); atomicAdd(&s_imp[3], p3);
    }
    __syncthreads();
    if (tid < NE) {
        s_base[tid] = atomicAdd(&counts[tid], s_cnt[tid]);  // reserve + count
        atomicAdd(&importance[tid], s_imp[tid]);
    }
    __syncthreads();
    if (lane < 16)
        order[bi * N_TOK + s_base[bi] + rk] = gt;
}

// ---------------------------------------------------------------------------
// Expert FFN v5: operand-swapped MFMA, FOUR quarter-FF passes.
// LDS 48.3 KB -> 3 blocks/CU (6 waves/SIMD). erf-GELU. lb block at end.
//   pass p: L1 over FF cols [p*128, p*128+128) (wave owns 16 cols) ->
//           packed ushort4 act -> barrier -> L2 partial accumulate.
// ---------------------------------------------------------------------------
__global__ __launch_bounds__(512, 6) void expert_mfma_kernel(
    const float* __restrict__ h,
    const unsigned short* __restrict__ w1p,
    const unsigned short* __restrict__ w2p,
    const float* __restrict__ b1, const float* __restrict__ b2,
    const float* __restrict__ top_prob,
    const int* __restrict__ order, const int* __restrict__ counts,
    const float* __restrict__ importance, float* __restrict__ out)
{
    __shared__ __align__(16) unsigned short sh_h[8 * 4 * 512];   // 32 KB
    __shared__ __align__(16) unsigned short sh_a[4 * 4 * 512];   // 16 KB
    __shared__ int s_tok[MT];

    const int tid = threadIdx.x;

    if (blockIdx.x == N_TOK / MT + NE) {      // lb block
        if (tid == 0) {
            double num = (double)importance[0] * counts[0] +
                         (double)importance[1] * counts[1] +
                         (double)importance[2] * counts[2] +
                         (double)importance[3] * counts[3];
            out[(size_t)N_TOK * HD] =
                (float)((double)NE * num / ((double)N_TOK * (double)N_TOK + 1e-8));
        }
        return;
    }

    int c = blockIdx.x, e;
    for (e = 0; e < NE; ++e) {
        int nch = (counts[e] + MT - 1) / MT;
        if (c < nch) break;
        c -= nch;
    }
    if (e >= NE) return;
    const int cnt  = counts[e];
    const int base = e * N_TOK + c * MT;
    const int nt   = min(MT, cnt - c * MT);

    if (tid < MT) s_tok[tid] = (tid < nt) ? order[base + tid] : -1;
    __syncthreads();

    // gather h rows -> frag-ordered bf16 LDS (B-frags: lane holds token=row)
    #pragma unroll
    for (int it = 0; it < 4; ++it) {
        int chunk = tid + it * 512;
        int tr = chunk >> 5, q = chunk & 31;
        int t = s_tok[tr];
        float4 v0 = make_float4(0.f,0.f,0.f,0.f), v1 = v0;
        if (t >= 0) {
            const float* p = &h[(size_t)t * HD + q * 8];
            v0 = *reinterpret_cast<const float4*>(p);
            v1 = *reinterpret_cast<const float4*>(p + 4);
        }
        short8 o;
        o[0] = (short)f2bf(v0.x); o[1] = (short)f2bf(v0.y);
        o[2] = (short)f2bf(v0.z); o[3] = (short)f2bf(v0.w);
        o[4] = (short)f2bf(v1.x); o[5] = (short)f2bf(v1.y);
        o[6] = (short)f2bf(v1.z); o[7] = (short)f2bf(v1.w);
        int ks = q >> 2, kg = q & 3, mi = tr >> 4, row = tr & 15;
        *reinterpret_cast<short8*>(&sh_h[((ks*4 + mi)*64 + kg*16 + row) * 8]) = o;
    }
    __syncthreads();

    const int lane  = tid & 63;
    const int wv    = tid >> 6;       // 0..7
    const int row15 = lane & 15;
    const int kg    = lane >> 4;

    const unsigned short* W1 = w1p + (size_t)e * 8 * 32 * 512;
    const unsigned short* W2 = w2p + (size_t)e * 16 * 16 * 512;

    // L2 accumulators: wave owns HD cols [wv*32, wv*32+32)
    f32x4 acc2[2][4];
    #pragma unroll
    for (int ni = 0; ni < 2; ++ni) {
        f32x4 bb = *reinterpret_cast<const f32x4*>(&b2[e * HD + wv * 32 + ni * 16 + kg * 4]);
        #pragma unroll
        for (int mi = 0; mi < 4; ++mi) acc2[ni][mi] = bb;
    }

    // act-write address components (n_local = wv*16 + kg*4 + r within pass)
    const int l_w   = wv >> 1;
    const int kg2_w = (wv & 1) * 2 + (kg >> 1);

    #pragma unroll
    for (int p = 0; p < 4; ++p) {
        // -------- L1 over FF quarter p: wave owns n-tile p*8+wv -----------
        f32x4 acc1[4];
        {
            f32x4 bb = *reinterpret_cast<const f32x4*>(
                &b1[e * FF + p * 128 + wv * 16 + kg * 4]);
            #pragma unroll
            for (int mi = 0; mi < 4; ++mi) acc1[mi] = bb;
        }
        #pragma unroll
        for (int ks = 0; ks < 8; ++ks) {
            short8 bh[4];
            #pragma unroll
            for (int mi = 0; mi < 4; ++mi)
                bh[mi] = *reinterpret_cast<const short8*>(&sh_h[((ks*4 + mi)*64 + lane) * 8]);
            short8 aw = *reinterpret_cast<const short8*>(
                &W1[(size_t)((ks*32 + p*8 + wv)*64 + lane) * 8]);
            #pragma unroll
            for (int mi = 0; mi < 4; ++mi)
                acc1[mi] = __builtin_amdgcn_mfma_f32_16x16x32_bf16(aw, bh[mi], acc1[mi], 0, 0, 0);
        }
        if (p > 0) __syncthreads();    // pass p-1's sh_a reads complete

        // -------- gelu + packed act write ---------------------------------
        #pragma unroll
        for (int mi = 0; mi < 4; ++mi) {
            ushort4 pk;
            pk.x = f2bf(gelu_f(acc1[mi][0]));
            pk.y = f2bf(gelu_f(acc1[mi][1]));
            pk.z = f2bf(gelu_f(acc1[mi][2]));
            pk.w = f2bf(gelu_f(acc1[mi][3]));
            *reinterpret_cast<ushort4*>(
                &sh_a[(((l_w*4 + mi)*64 + kg2_w*16 + row15) * 8 + (kg & 1) * 4)]) = pk;
        }
        __syncthreads();

        // -------- L2 partial over this FF quarter -------------------------
        #pragma unroll
        for (int l2 = 0; l2 < 4; ++l2) {
            short8 ba[4];
            #pragma unroll
            for (int mi = 0; mi < 4; ++mi)
                ba[mi] = *reinterpret_cast<const short8*>(&sh_a[((l2*4 + mi)*64 + lane) * 8]);
            #pragma unroll
            for (int ni = 0; ni < 2; ++ni) {
                short8 aw = *reinterpret_cast<const short8*>(
                    &W2[(size_t)(((p*4 + l2)*16 + wv*2 + ni)*64 + lane) * 8]);
                #pragma unroll
                for (int mi = 0; mi < 4; ++mi)
                    acc2[ni][mi] = __builtin_amdgcn_mfma_f32_16x16x32_bf16(aw, ba[mi], acc2[ni][mi], 0, 0, 0);
            }
        }
    }

    // -------- epilogue: float4 residual + store ---------------------------
    #pragma unroll
    for (int mi = 0; mi < 4; ++mi) {
        int gt = s_tok[mi * 16 + row15];
        if (gt < 0) continue;
        float tp = 0.5f * top_prob[gt];
        #pragma unroll
        for (int ni = 0; ni < 2; ++ni) {
            int nb = wv * 32 + ni * 16 + kg * 4;
            float4 res = *reinterpret_cast<const float4*>(&h[(size_t)gt * HD + nb]);
            float4 o;
            o.x = res.x + tp * acc2[ni][mi][0];
            o.y = res.y + tp * acc2[ni][mi][1];
            o.z = res.z + tp * acc2[ni][mi][2];
            o.w = res.w + tp * acc2[ni][mi][3];
            *reinterpret_cast<float4*>(&out[(size_t)gt * HD + nb]) = o;
        }
    }
}

// ---------------------------------------------------------------------------
extern "C" void kernel_launch(void* const* d_in, const int* in_sizes, int n_in,
                              void* d_out, int out_size, void* d_ws, size_t ws_size,
                              hipStream_t stream)
{
    const float* h        = (const float*)d_in[0];
    const float* tok_emb  = (const float*)d_in[1];
    /* d_in[2] = is_mask: all zeros, unused by the reference math */
    const float* ln_g     = (const float*)d_in[3];
    const float* ln_b     = (const float*)d_in[4];
    const float* geom_w   = (const float*)d_in[5];
    const float* geom_b   = (const float*)d_in[6];
    const float* fuse_w   = (const float*)d_in[7];
    const float* fuse_b   = (const float*)d_in[8];
    const float* router_w = (const float*)d_in[9];
    const float* router_b = (const float*)d_in[10];
    const float* w1       = (const float*)d_in[11];
    const float* b1       = (const float*)d_in[12];
    const float* w2       = (const float*)d_in[13];
    const float* b2       = (const float*)d_in[14];
    float* out = (float*)d_out;

    // workspace layout (4B word units from d_ws)
    int*   counts     = (int*)d_ws;                        // [4]
    float* importance = (float*)d_ws + 4;                  // [4]
    float* top_prob   = (float*)d_ws + 64;                 // [N]
    int*   order      = (int*)d_ws + 64 + N_TOK;           // [4*N] regions
    unsigned short* w1p = (unsigned short*)((int*)d_ws + 64 + 5 * N_TOK); // 1MB
    unsigned short* w2p = w1p + (size_t)NE * FF * HD;                     // 1MB
    _Float16* wg_hi = (_Float16*)(w2p + (size_t)NE * FF * HD);
    _Float16* wg_lo = wg_hi + 8192;
    _Float16* wf_hi = wg_lo + 8192;
    _Float16* wf_lo = wf_hi + 4096;
    _Float16* wr_hi = wf_lo + 4096;
    _Float16* wr_lo = wr_hi + 1024;
    float*    gb2   = (float*)(wr_lo + 1024);              // [32]

    hipMemsetAsync(d_ws, 0, 64 * sizeof(int), stream);

    prep_all_kernel<<<519, 256, 0, stream>>>(
        w1, w2, w1p, w2p,
        geom_w, geom_b, ln_g, ln_b, fuse_w, router_w,
        wg_hi, wg_lo, wf_hi, wf_lo, wr_hi, wr_lo, gb2);

    router3_kernel<<<N_TOK / 64, 256, 0, stream>>>(
        h, tok_emb, wg_hi, wg_lo, wf_hi, wf_lo, wr_hi, wr_lo,
        gb2, fuse_b, router_b, top_prob, order, counts, importance);

    expert_mfma_kernel<<<N_TOK / MT + NE + 1, 512, 0, stream>>>(
        h, w1p, w2p, b1, b2, top_prob, order, counts, importance, out);
}